// Round 9
// baseline (100.521 us; speedup 1.0000x reference)
//
#include <hip/hip_runtime.h>

#define NB 8
#define TE 256
#define TD 256
#define DE 512
#define QT 4

// K2 = 2*log2(e): exp2(K2*x) = e^{2x}; tanh(x) = 1 - 2/(e^{2x}+1).
#define K2SCALE 2.8853900817779268f

typedef short bf16x8 __attribute__((ext_vector_type(8)));           // 8 bf16 (4 VGPR)
typedef float f32x4 __attribute__((ext_vector_type(4)));            // MFMA acc
typedef unsigned short u16x8 __attribute__((ext_vector_type(8)));   // 16 B staging

// round-to-nearest-even f32 -> bf16
static __device__ __forceinline__ unsigned short f2bf(float x) {
  unsigned int u = __float_as_uint(x);
  u += 0x7fffu + ((u >> 16) & 1u);
  return (unsigned short)(u >> 16);
}

// split f32 -> hi (ROUNDED bf16) + lo (rounded residual).
static __device__ __forceinline__ void split8(
    const float4& x0, const float4& x1, u16x8& h, u16x8& l) {
  float xs[8] = {x0.x, x0.y, x0.z, x0.w, x1.x, x1.y, x1.z, x1.w};
  #pragma unroll
  for (int j = 0; j < 8; ++j) {
    unsigned short hh = f2bf(xs[j]);
    float hf = __uint_as_float((unsigned int)hh << 16);
    h[j] = hh;
    l[j] = f2bf(xs[j] - hf);
  }
}

// ---- convB: W [512x512] f32 -> TRANSPOSED hi/lo bf16 BT[n][k] (32x32 tiles) ----
__global__ __launch_bounds__(256) void convB(
    const float* __restrict__ w0, unsigned short* __restrict__ h0, unsigned short* __restrict__ l0,
    const float* __restrict__ w1, unsigned short* __restrict__ h1, unsigned short* __restrict__ l1)
{
  const float* W = blockIdx.z ? w1 : w0;
  unsigned short* H = blockIdx.z ? h1 : h0;
  unsigned short* L = blockIdx.z ? l1 : l0;
  __shared__ unsigned short sh[32][33], sl[32][33];
  const int t = threadIdx.x;
  const int k0 = blockIdx.y * 32, n0 = blockIdx.x * 32;
  const int r = t >> 3, c = (t & 7) * 4;
  float4 x = *(const float4*)(W + (size_t)(k0 + r) * DE + n0 + c);
  float xs[4] = {x.x, x.y, x.z, x.w};
  #pragma unroll
  for (int j = 0; j < 4; ++j) {
    unsigned short hh = f2bf(xs[j]);
    float hf = __uint_as_float((unsigned int)hh << 16);
    sh[r][c + j] = hh;
    sl[r][c + j] = f2bf(xs[j] - hf);
  }
  __syncthreads();
  ushort4 oh, ol;
  oh.x = sh[c + 0][r]; oh.y = sh[c + 1][r]; oh.z = sh[c + 2][r]; oh.w = sh[c + 3][r];
  ol.x = sl[c + 0][r]; ol.y = sl[c + 1][r]; ol.z = sl[c + 2][r]; ol.w = sl[c + 3][r];
  *(ushort4*)(H + (size_t)(n0 + r) * DE + k0 + c) = oh;
  *(ushort4*)(L + (size_t)(n0 + r) * DE + k0 + c) = ol;
}

// ---- gemm_mfma: C = exp2(K2 * A@B), A f32 split in-register, dbuf LDS ---------
// (byte-identical to R7: XCD-clustered 1D-512 grid)
__global__ __launch_bounds__(256) void gemm_mfma(
    const float* __restrict__ A0,
    const unsigned short* __restrict__ BH0, const unsigned short* __restrict__ BL0,
    float* __restrict__ C0,
    const float* __restrict__ A1,
    const unsigned short* __restrict__ BH1, const unsigned short* __restrict__ BL1,
    float* __restrict__ C1)
{
  const int blk = blockIdx.x;
  const int xcd = blk & 7;
  const int j = blk >> 3;                   // 0..63
  const int panel = xcd * 8 + (j & 7);      // 0..63: (m-block, matrix) pair
  const int bx = j >> 3;                    // 0..7  n-block
  const int by = panel & 31;                // 0..31 m-block
  const int bz = panel >> 5;                // 0..1  matrix select
  const float*          A  = bz ? A1  : A0;
  const unsigned short* BH = bz ? BH1 : BH0;
  const unsigned short* BL = bz ? BL1 : BL0;
  float*                C  = bz ? C1  : C0;
  const int tid  = threadIdx.x;
  const int lane = tid & 63;
  const int wave = tid >> 6;
  const int wm = wave >> 1, wn = wave & 1;
  const int g = lane >> 4, r16 = lane & 15;
  const int m0 = by * 64, n0 = bx * 64;
  __shared__ __align__(16) unsigned short Ah[2][64][40], Al[2][64][40];
  __shared__ __align__(16) unsigned short Bh[2][64][40], Bl[2][64][40];
  const int arow = tid >> 2;            // 0..63
  const int apart = (tid & 3) * 8;      // 8-elem (16 B) piece of a 32-elem row

  float4 a00, a01;
  u16x8 pb, plb;
#define LOADTILE(KT) do {                                                   \
    const size_t ko = (size_t)(KT) * 32 + apart;                            \
    const float* pa_ = A + (size_t)(m0 + arow) * 512 + ko;                  \
    a00 = *(const float4*)pa_;  a01 = *(const float4*)(pa_ + 4);            \
    pb  = *(const u16x8*)(BH + (size_t)(n0 + arow) * 512 + ko);             \
    plb = *(const u16x8*)(BL + (size_t)(n0 + arow) * 512 + ko);             \
  } while (0)
#define STORETILE(BUF) do {                                                 \
    u16x8 h0_, l0_;                                                         \
    split8(a00, a01, h0_, l0_);                                             \
    *(u16x8*)&Ah[BUF][arow][apart] = h0_;                                   \
    *(u16x8*)&Al[BUF][arow][apart] = l0_;                                   \
    *(u16x8*)&Bh[BUF][arow][apart] = pb;                                    \
    *(u16x8*)&Bl[BUF][arow][apart] = plb;                                   \
  } while (0)

  f32x4 accm[2][2], acce[2][2];
  #pragma unroll
  for (int mt = 0; mt < 2; ++mt)
    #pragma unroll
    for (int nt = 0; nt < 2; ++nt) {
      accm[mt][nt] = (f32x4){0.f, 0.f, 0.f, 0.f};
      acce[mt][nt] = (f32x4){0.f, 0.f, 0.f, 0.f};
    }

  LOADTILE(0);
  STORETILE(0);
  __syncthreads();

  for (int kt = 0; kt < 16; ++kt) {
    const int cur = kt & 1;
    if (kt + 1 < 16) LOADTILE(kt + 1);  // issue early; hides under compute
    bf16x8 ah[2], al[2], bh[2], bl[2];
    #pragma unroll
    for (int mt = 0; mt < 2; ++mt) {
      ah[mt] = *(const bf16x8*)&Ah[cur][wm * 32 + mt * 16 + r16][g * 8];
      al[mt] = *(const bf16x8*)&Al[cur][wm * 32 + mt * 16 + r16][g * 8];
    }
    #pragma unroll
    for (int nt = 0; nt < 2; ++nt) {
      bh[nt] = *(const bf16x8*)&Bh[cur][wn * 32 + nt * 16 + r16][g * 8];
      bl[nt] = *(const bf16x8*)&Bl[cur][wn * 32 + nt * 16 + r16][g * 8];
    }
    #pragma unroll
    for (int mt = 0; mt < 2; ++mt)
      #pragma unroll
      for (int nt = 0; nt < 2; ++nt) {
        accm[mt][nt] = __builtin_amdgcn_mfma_f32_16x16x32_bf16(ah[mt], bh[nt], accm[mt][nt], 0, 0, 0);
        acce[mt][nt] = __builtin_amdgcn_mfma_f32_16x16x32_bf16(al[mt], bh[nt], acce[mt][nt], 0, 0, 0);
        acce[mt][nt] = __builtin_amdgcn_mfma_f32_16x16x32_bf16(ah[mt], bl[nt], acce[mt][nt], 0, 0, 0);
      }
    if (kt + 1 < 16) STORETILE(cur ^ 1);  // other buffer: no hazard
    __syncthreads();                       // single barrier per k-tile
  }
#undef LOADTILE
#undef STORETILE

  #pragma unroll
  for (int mt = 0; mt < 2; ++mt)
    #pragma unroll
    for (int nt = 0; nt < 2; ++nt)
      #pragma unroll
      for (int jj = 0; jj < 4; ++jj) {
        float vsum = accm[mt][nt][jj] + acce[mt][nt][jj];
        int row = m0 + wm * 32 + mt * 16 + g * 4 + jj;
        int col = n0 + wn * 32 + nt * 16 + r16;
        C[(size_t)row * 512 + col] = __builtin_amdgcn_exp2f(vsum * K2SCALE);
      }
}

// ---------------- fused scores + softmax + context -----------------------------
// 1024 threads (16 waves) per block, grid 512 = 2 blocks/CU -> 32 waves/CU =
// 8 waves/SIMD (vs 4 before; VGPR=44 allows it, grid was the limiter).
// Each wave owns 16 t in the score phase; context uses 8 t-groups of 32.
// b = blk&7 keeps ws[b]/enc[b] XCD-local (R7, FETCH_SIZE 35->6.2 GB).
__global__ __launch_bounds__(1024, 8) void attn(
    const float* __restrict__ ws, const float* __restrict__ uh,
    const float* __restrict__ enc, const float* __restrict__ va,
    float* __restrict__ out_c, float* __restrict__ out_e)
{
  const int tid  = threadIdx.x;
  const int wave = tid >> 6;               // 0..15
  const int lane = tid & 63;
  const int b  = blockIdx.x & 7;           // XCD-locality: batch <-> XCD
  const int q0 = (blockIdx.x >> 3) * QT;
  __shared__ float s_sc[QT][TE];           // 4 KB
  __shared__ float red[7][QT][DE];         // 56 KB, context partials
  const int fbase = lane * 8;              // lane owns 8 contiguous f

  float4 v0 = *(const float4*)(va + fbase);
  float4 v1 = *(const float4*)(va + fbase + 4);
  float v[8] = {v0.x, v0.y, v0.z, v0.w, v1.x, v1.y, v1.z, v1.w};

  float eu[QT][8];
  #pragma unroll
  for (int q = 0; q < QT; ++q) {
    const float* up = uh + (size_t)(b * TD + q0 + q) * DE + fbase;
    float4 u0 = *(const float4*)(up);
    float4 u1 = *(const float4*)(up + 4);
    eu[q][0] = u0.x; eu[q][1] = u0.y; eu[q][2] = u0.z; eu[q][3] = u0.w;
    eu[q][4] = u1.x; eu[q][5] = u1.y; eu[q][6] = u1.z; eu[q][7] = u1.w;
  }

  // ---- scores: wave owns t in [wave*16, wave*16+16), 1-deep prefetch on ws ----
  const int t0 = wave * 16;
  const float* wp = ws + (size_t)(b * TE + t0) * DE + fbase;
  float4 w0 = *(const float4*)(wp);
  float4 w1 = *(const float4*)(wp + 4);
  for (int t = t0; t < t0 + 16; ++t) {
    float cw[8] = {w0.x, w0.y, w0.z, w0.w, w1.x, w1.y, w1.z, w1.w};
    // prefetch next row; last iter (wave 15, t=255) reads one row past ws[7]
    // which is uh[0] -- still inside the workspace allocation -- and unused.
    wp += DE;
    w0 = *(const float4*)(wp);
    w1 = *(const float4*)(wp + 4);
    float a[QT];
    #pragma unroll
    for (int q = 0; q < QT; ++q) {
      float A0 = fmaf(cw[0], eu[q][0], 1.f);
      float A1 = fmaf(cw[1], eu[q][1], 1.f);
      float A2 = fmaf(cw[2], eu[q][2], 1.f);
      float A3 = fmaf(cw[3], eu[q][3], 1.f);
      float B0 = fmaf(cw[4], eu[q][4], 1.f);
      float B1 = fmaf(cw[5], eu[q][5], 1.f);
      float B2 = fmaf(cw[6], eu[q][6], 1.f);
      float B3 = fmaf(cw[7], eu[q][7], 1.f);
      float n1 = fmaf(v[1], A0, v[0] * A1);
      float d1 = A0 * A1;
      float n2 = fmaf(v[3], A2, v[2] * A3);
      float d2 = A2 * A3;
      float N1 = fmaf(n2, d1, n1 * d2);
      float D1 = d1 * d2;
      float n3 = fmaf(v[5], B0, v[4] * B1);
      float d3 = B0 * B1;
      float n4 = fmaf(v[7], B2, v[6] * B3);
      float d4 = B2 * B3;
      float N2 = fmaf(n4, d3, n3 * d4);
      float D2 = d3 * d4;
      float s = N1 * __builtin_amdgcn_rcpf(D1);
      a[q] = fmaf(N2, __builtin_amdgcn_rcpf(D2), s);
    }
    {
      const bool h1 = lane & 1;
      float m0 = h1 ? a[1] : a[0], o0 = h1 ? a[0] : a[1];
      float m1 = h1 ? a[3] : a[2], o1 = h1 ? a[2] : a[3];
      float r0 = m0 + __shfl_xor(o0, 1, 64);
      float r1 = m1 + __shfl_xor(o1, 1, 64);
      const bool h2 = lane & 2;
      float mm = h2 ? r1 : r0, oo = h2 ? r0 : r1;
      float r = mm + __shfl_xor(oo, 2, 64);
      r += __shfl_xor(r, 4, 64);
      r += __shfl_xor(r, 8, 64);
      r += __shfl_xor(r, 16, 64);
      r += __shfl_xor(r, 32, 64);
      if (lane < QT) s_sc[lane][t] = -2.f * r;
    }
  }
  __syncthreads();

  // ---- softmax: waves 0..3 handle row = wave; others wait ----
  if (wave < QT) {
    const int r = wave;
    float x[4];
    #pragma unroll
    for (int i = 0; i < 4; ++i) x[i] = s_sc[r][lane + 64 * i];
    float m = fmaxf(fmaxf(x[0], x[1]), fmaxf(x[2], x[3]));
    #pragma unroll
    for (int off = 32; off >= 1; off >>= 1) m = fmaxf(m, __shfl_xor(m, off, 64));
    const float L2E = 1.4426950408889634f;
    float ssum = 0.f;
    #pragma unroll
    for (int i = 0; i < 4; ++i) { x[i] = __builtin_amdgcn_exp2f((x[i] - m) * L2E); ssum += x[i]; }
    #pragma unroll
    for (int off = 32; off >= 1; off >>= 1) ssum += __shfl_xor(ssum, off, 64);
    float inv = 1.f / ssum;
    float* oe = out_e + (size_t)(b * TD + q0 + r) * TE;
    #pragma unroll
    for (int i = 0; i < 4; ++i) {
      float e = x[i] * inv;
      s_sc[r][lane + 64 * i] = e;
      oe[lane + 64 * i] = e;
    }
  }
  __syncthreads();

  // ---- context: c[q][f4..f4+3] = sum_t e[q][t]*enc[b][t][f4..f4+3] ----
  // thread owns f4 = (tid&127)*4 and t-group (tid>>7) of 32 t; LDS reduce.
  {
    const int fgrp = tid >> 7;           // 0..7
    const int f4   = (tid & 127) * 4;
    float4 c[QT];
    #pragma unroll
    for (int q = 0; q < QT; ++q) c[q] = make_float4(0.f, 0.f, 0.f, 0.f);
    const float* eb = enc + (size_t)b * TE * DE + f4;
    const int tb = fgrp * 32;
    #pragma unroll 4
    for (int t = tb; t < tb + 32; ++t) {
      float4 ee = *(const float4*)(eb + (size_t)t * DE);
      #pragma unroll
      for (int q = 0; q < QT; ++q) {
        float w = s_sc[q][t];
        c[q].x = fmaf(w, ee.x, c[q].x);
        c[q].y = fmaf(w, ee.y, c[q].y);
        c[q].z = fmaf(w, ee.z, c[q].z);
        c[q].w = fmaf(w, ee.w, c[q].w);
      }
    }
    if (fgrp > 0) {
      #pragma unroll
      for (int q = 0; q < QT; ++q) *(float4*)&red[fgrp - 1][q][f4] = c[q];
    }
    __syncthreads();
    if (fgrp == 0) {
      #pragma unroll
      for (int q = 0; q < QT; ++q) {
        float4 acc = c[q];
        #pragma unroll
        for (int p = 0; p < 7; ++p) {
          float4 rr = *(const float4*)&red[p][q][f4];
          acc.x += rr.x; acc.y += rr.y; acc.z += rr.z; acc.w += rr.w;
        }
        *(float4*)(out_c + (size_t)(b * TD + q0 + q) * DE + f4) = acc;
      }
    }
  }
}

extern "C" void kernel_launch(void* const* d_in, const int* in_sizes, int n_in,
                              void* d_out, int out_size, void* d_ws, size_t ws_size,
                              hipStream_t stream) {
  const float* enc = (const float*)d_in[0];
  const float* dec = (const float*)d_in[1];
  const float* Wa  = (const float*)d_in[2];
  const float* Ua  = (const float*)d_in[3];
  const float* Va  = (const float*)d_in[4];
  float* out_c = (float*)d_out;
  float* out_e = out_c + (size_t)NB * TD * DE;          // c first, then e

  // workspace layout (10 MB):
  float* ws = (float*)d_ws;                             // ew = e^{2Ws}: 4 MB
  float* uh = ws + 1048576;                             // eu = e^{2Uh}: 4 MB
  unsigned short* BHw = (unsigned short*)(uh + 1048576);// 0.5 MB each
  unsigned short* BLw = BHw + 262144;
  unsigned short* BHu = BLw + 262144;
  unsigned short* BLu = BHu + 262144;

  convB<<<dim3(16, 16, 2), dim3(256), 0, stream>>>(Wa, BHw, BLw, Ua, BHu, BLu);
  gemm_mfma<<<dim3(512), dim3(256), 0, stream>>>(
      enc, BHw, BLw, ws, dec, BHu, BLu, uh);
  attn<<<dim3(NB * (TD / QT)), dim3(1024), 0, stream>>>(
      ws, uh, enc, Va, out_c, out_e);
}

// Round 10
// 71.257 us; speedup vs baseline: 1.4107x; 1.4107x over previous
//
#include <hip/hip_runtime.h>

#define NB 8
#define TE 256
#define TD 256
#define DE 512
#define QT 4

// K2 = 2*log2(e): exp2(K2*x) = e^{2x}; tanh(x) = 1 - 2/(e^{2x}+1).
#define K2SCALE 2.8853900817779268f

typedef short bf16x8 __attribute__((ext_vector_type(8)));           // 8 bf16 (4 VGPR)
typedef float f32x4 __attribute__((ext_vector_type(4)));            // MFMA acc
typedef unsigned short u16x8 __attribute__((ext_vector_type(8)));   // 16 B staging

// round-to-nearest-even f32 -> bf16
static __device__ __forceinline__ unsigned short f2bf(float x) {
  unsigned int u = __float_as_uint(x);
  u += 0x7fffu + ((u >> 16) & 1u);
  return (unsigned short)(u >> 16);
}

// split f32 -> hi (ROUNDED bf16) + lo (rounded residual).
static __device__ __forceinline__ void split8(
    const float4& x0, const float4& x1, u16x8& h, u16x8& l) {
  float xs[8] = {x0.x, x0.y, x0.z, x0.w, x1.x, x1.y, x1.z, x1.w};
  #pragma unroll
  for (int j = 0; j < 8; ++j) {
    unsigned short hh = f2bf(xs[j]);
    float hf = __uint_as_float((unsigned int)hh << 16);
    h[j] = hh;
    l[j] = f2bf(xs[j] - hf);
  }
}

// ---- convB: W [512x512] f32 -> TRANSPOSED hi/lo bf16 BT[n][k] (32x32 tiles) ----
__global__ __launch_bounds__(256) void convB(
    const float* __restrict__ w0, unsigned short* __restrict__ h0, unsigned short* __restrict__ l0,
    const float* __restrict__ w1, unsigned short* __restrict__ h1, unsigned short* __restrict__ l1)
{
  const float* W = blockIdx.z ? w1 : w0;
  unsigned short* H = blockIdx.z ? h1 : h0;
  unsigned short* L = blockIdx.z ? l1 : l0;
  __shared__ unsigned short sh[32][33], sl[32][33];
  const int t = threadIdx.x;
  const int k0 = blockIdx.y * 32, n0 = blockIdx.x * 32;
  const int r = t >> 3, c = (t & 7) * 4;
  float4 x = *(const float4*)(W + (size_t)(k0 + r) * DE + n0 + c);
  float xs[4] = {x.x, x.y, x.z, x.w};
  #pragma unroll
  for (int j = 0; j < 4; ++j) {
    unsigned short hh = f2bf(xs[j]);
    float hf = __uint_as_float((unsigned int)hh << 16);
    sh[r][c + j] = hh;
    sl[r][c + j] = f2bf(xs[j] - hf);
  }
  __syncthreads();
  ushort4 oh, ol;
  oh.x = sh[c + 0][r]; oh.y = sh[c + 1][r]; oh.z = sh[c + 2][r]; oh.w = sh[c + 3][r];
  ol.x = sl[c + 0][r]; ol.y = sl[c + 1][r]; ol.z = sl[c + 2][r]; ol.w = sl[c + 3][r];
  *(ushort4*)(H + (size_t)(n0 + r) * DE + k0 + c) = oh;
  *(ushort4*)(L + (size_t)(n0 + r) * DE + k0 + c) = ol;
}

// ---- gemm_mfma: C = exp2(K2 * A@B), A f32 split in-register, dbuf LDS ---------
// BM=64 BN=32 KT=32, 256 thr (4 waves, each owns a 16x32 sub-tile = 2x 16x16
// frags x 3 split terms = 6 MFMA/kt). grid 1024 -> 4 blocks/CU (30 KB LDS) =
// 4 waves/SIMD: doubles latency-hiding vs R7's 2/SIMD (gemm was stall-bound:
// ~220 cy issue/kt vs ~500 cy exposed load+barrier latency with 2 waves).
// XCD-clustered decode: the 16 n-blocks sharing an A-panel sit on one XCD.
__global__ __launch_bounds__(256) void gemm_mfma(
    const float* __restrict__ A0,
    const unsigned short* __restrict__ BH0, const unsigned short* __restrict__ BL0,
    float* __restrict__ C0,
    const float* __restrict__ A1,
    const unsigned short* __restrict__ BH1, const unsigned short* __restrict__ BL1,
    float* __restrict__ C1)
{
  const int blk = blockIdx.x;               // 0..1023
  const int xcd = blk & 7;
  const int j = blk >> 3;                   // 0..127
  const int panel = xcd * 8 + (j & 7);      // 0..63: (m-block, matrix) pair
  const int bx = j >> 3;                    // 0..15 n-block
  const int by = panel & 31;                // 0..31 m-block
  const int bz = panel >> 5;                // 0..1  matrix select
  const float*          A  = bz ? A1  : A0;
  const unsigned short* BH = bz ? BH1 : BH0;
  const unsigned short* BL = bz ? BL1 : BL0;
  float*                C  = bz ? C1  : C0;
  const int tid  = threadIdx.x;
  const int lane = tid & 63;
  const int wave = tid >> 6;                // 0..3 = m sub-tile
  const int g = lane >> 4, r16 = lane & 15;
  const int m0 = by * 64, n0 = bx * 32;
  __shared__ __align__(16) unsigned short Ah[2][64][40], Al[2][64][40];  // 20 KB
  __shared__ __align__(16) unsigned short Bh[2][32][40], Bl[2][32][40];  // 10 KB
  const int arow = tid >> 2;            // 0..63
  const int apart = (tid & 3) * 8;      // 8-elem (16 B) piece of a 32-elem row
  const int brow = (tid & 127) >> 2;    // 0..31 (threads 0..127 stage B)
  const bool doB = tid < 128;

  float4 a00, a01;
  u16x8 pb, plb;
#define LOADTILE(KT) do {                                                   \
    const size_t ko = (size_t)(KT) * 32 + apart;                            \
    const float* pa_ = A + (size_t)(m0 + arow) * 512 + ko;                  \
    a00 = *(const float4*)pa_;  a01 = *(const float4*)(pa_ + 4);            \
    if (doB) {                                                              \
      pb  = *(const u16x8*)(BH + (size_t)(n0 + brow) * 512 + ko);           \
      plb = *(const u16x8*)(BL + (size_t)(n0 + brow) * 512 + ko);           \
    }                                                                       \
  } while (0)
#define STORETILE(BUF) do {                                                 \
    u16x8 h0_, l0_;                                                         \
    split8(a00, a01, h0_, l0_);                                             \
    *(u16x8*)&Ah[BUF][arow][apart] = h0_;                                   \
    *(u16x8*)&Al[BUF][arow][apart] = l0_;                                   \
    if (doB) {                                                              \
      *(u16x8*)&Bh[BUF][brow][apart] = pb;                                  \
      *(u16x8*)&Bl[BUF][brow][apart] = plb;                                 \
    }                                                                       \
  } while (0)

  f32x4 accm[2], acce[2];
  #pragma unroll
  for (int nt = 0; nt < 2; ++nt) {
    accm[nt] = (f32x4){0.f, 0.f, 0.f, 0.f};
    acce[nt] = (f32x4){0.f, 0.f, 0.f, 0.f};
  }

  LOADTILE(0);
  STORETILE(0);
  __syncthreads();

  for (int kt = 0; kt < 16; ++kt) {
    const int cur = kt & 1;
    if (kt + 1 < 16) LOADTILE(kt + 1);  // issue early; hides under compute
    bf16x8 ah, al, bh[2], bl[2];
    ah = *(const bf16x8*)&Ah[cur][wave * 16 + r16][g * 8];
    al = *(const bf16x8*)&Al[cur][wave * 16 + r16][g * 8];
    #pragma unroll
    for (int nt = 0; nt < 2; ++nt) {
      bh[nt] = *(const bf16x8*)&Bh[cur][nt * 16 + r16][g * 8];
      bl[nt] = *(const bf16x8*)&Bl[cur][nt * 16 + r16][g * 8];
    }
    #pragma unroll
    for (int nt = 0; nt < 2; ++nt) {
      accm[nt] = __builtin_amdgcn_mfma_f32_16x16x32_bf16(ah, bh[nt], accm[nt], 0, 0, 0);
      acce[nt] = __builtin_amdgcn_mfma_f32_16x16x32_bf16(al, bh[nt], acce[nt], 0, 0, 0);
      acce[nt] = __builtin_amdgcn_mfma_f32_16x16x32_bf16(ah, bl[nt], acce[nt], 0, 0, 0);
    }
    if (kt + 1 < 16) STORETILE(cur ^ 1);  // other buffer: no hazard
    __syncthreads();                       // single barrier per k-tile
  }
#undef LOADTILE
#undef STORETILE

  #pragma unroll
  for (int nt = 0; nt < 2; ++nt)
    #pragma unroll
    for (int jj = 0; jj < 4; ++jj) {
      float vsum = accm[nt][jj] + acce[nt][jj];
      int row = m0 + wave * 16 + g * 4 + jj;
      int col = n0 + nt * 16 + r16;
      C[(size_t)row * 512 + col] = __builtin_amdgcn_exp2f(vsum * K2SCALE);
    }
}

// ---------------- fused scores + softmax + context (R7-exact, proven 47.8us) ---
__global__ __launch_bounds__(512) void attn(
    const float* __restrict__ ws, const float* __restrict__ uh,
    const float* __restrict__ enc, const float* __restrict__ va,
    float* __restrict__ out_c, float* __restrict__ out_e)
{
  const int tid  = threadIdx.x;
  const int wave = tid >> 6;
  const int lane = tid & 63;
  const int b  = blockIdx.x & 7;           // XCD-locality: batch <-> XCD
  const int q0 = (blockIdx.x >> 3) * QT;
  __shared__ float s_sc[QT][TE];           // 4 KB
  __shared__ float red[3][QT][DE];         // 24 KB, context partials
  const int fbase = lane * 8;              // lane owns 8 contiguous f

  float4 v0 = *(const float4*)(va + fbase);
  float4 v1 = *(const float4*)(va + fbase + 4);
  float v[8] = {v0.x, v0.y, v0.z, v0.w, v1.x, v1.y, v1.z, v1.w};

  float eu[QT][8];
  #pragma unroll
  for (int q = 0; q < QT; ++q) {
    const float* up = uh + (size_t)(b * TD + q0 + q) * DE + fbase;
    float4 u0 = *(const float4*)(up);
    float4 u1 = *(const float4*)(up + 4);
    eu[q][0] = u0.x; eu[q][1] = u0.y; eu[q][2] = u0.z; eu[q][3] = u0.w;
    eu[q][4] = u1.x; eu[q][5] = u1.y; eu[q][6] = u1.z; eu[q][7] = u1.w;
  }

  // ---- scores: wave owns t in [wave*32, wave*32+32), 1-deep prefetch on ws ----
  const int t0 = wave * 32;
  const float* wp = ws + (size_t)(b * TE + t0) * DE + fbase;
  float4 w0 = *(const float4*)(wp);
  float4 w1 = *(const float4*)(wp + 4);
  for (int t = t0; t < t0 + 32; ++t) {
    float cw[8] = {w0.x, w0.y, w0.z, w0.w, w1.x, w1.y, w1.z, w1.w};
    // prefetch next row; last iteration reads one row past (lands in uh[0],
    // still inside the same workspace allocation) and is unused.
    wp += DE;
    w0 = *(const float4*)(wp);
    w1 = *(const float4*)(wp + 4);
    float a[QT];
    #pragma unroll
    for (int q = 0; q < QT; ++q) {
      float A0 = fmaf(cw[0], eu[q][0], 1.f);
      float A1 = fmaf(cw[1], eu[q][1], 1.f);
      float A2 = fmaf(cw[2], eu[q][2], 1.f);
      float A3 = fmaf(cw[3], eu[q][3], 1.f);
      float B0 = fmaf(cw[4], eu[q][4], 1.f);
      float B1 = fmaf(cw[5], eu[q][5], 1.f);
      float B2 = fmaf(cw[6], eu[q][6], 1.f);
      float B3 = fmaf(cw[7], eu[q][7], 1.f);
      float n1 = fmaf(v[1], A0, v[0] * A1);
      float d1 = A0 * A1;
      float n2 = fmaf(v[3], A2, v[2] * A3);
      float d2 = A2 * A3;
      float N1 = fmaf(n2, d1, n1 * d2);
      float D1 = d1 * d2;
      float n3 = fmaf(v[5], B0, v[4] * B1);
      float d3 = B0 * B1;
      float n4 = fmaf(v[7], B2, v[6] * B3);
      float d4 = B2 * B3;
      float N2 = fmaf(n4, d3, n3 * d4);
      float D2 = d3 * d4;
      float s = N1 * __builtin_amdgcn_rcpf(D1);
      a[q] = fmaf(N2, __builtin_amdgcn_rcpf(D2), s);
    }
    {
      const bool h1 = lane & 1;
      float m0 = h1 ? a[1] : a[0], o0 = h1 ? a[0] : a[1];
      float m1 = h1 ? a[3] : a[2], o1 = h1 ? a[2] : a[3];
      float r0 = m0 + __shfl_xor(o0, 1, 64);
      float r1 = m1 + __shfl_xor(o1, 1, 64);
      const bool h2 = lane & 2;
      float mm = h2 ? r1 : r0, oo = h2 ? r0 : r1;
      float r = mm + __shfl_xor(oo, 2, 64);
      r += __shfl_xor(r, 4, 64);
      r += __shfl_xor(r, 8, 64);
      r += __shfl_xor(r, 16, 64);
      r += __shfl_xor(r, 32, 64);
      if (lane < QT) s_sc[lane][t] = -2.f * r;
    }
  }
  __syncthreads();

  // ---- softmax: waves 0..3 handle row = wave; waves 4..7 wait ----
  if (wave < QT) {
    const int r = wave;
    float x[4];
    #pragma unroll
    for (int i = 0; i < 4; ++i) x[i] = s_sc[r][lane + 64 * i];
    float m = fmaxf(fmaxf(x[0], x[1]), fmaxf(x[2], x[3]));
    #pragma unroll
    for (int off = 32; off >= 1; off >>= 1) m = fmaxf(m, __shfl_xor(m, off, 64));
    const float L2E = 1.4426950408889634f;
    float ssum = 0.f;
    #pragma unroll
    for (int i = 0; i < 4; ++i) { x[i] = __builtin_amdgcn_exp2f((x[i] - m) * L2E); ssum += x[i]; }
    #pragma unroll
    for (int off = 32; off >= 1; off >>= 1) ssum += __shfl_xor(ssum, off, 64);
    float inv = 1.f / ssum;
    float* oe = out_e + (size_t)(b * TD + q0 + r) * TE;
    #pragma unroll
    for (int i = 0; i < 4; ++i) {
      float e = x[i] * inv;
      s_sc[r][lane + 64 * i] = e;
      oe[lane + 64 * i] = e;
    }
  }
  __syncthreads();

  // ---- context: c[q][f4..f4+3] = sum_t e[q][t]*enc[b][t][f4..f4+3] ----
  {
    const int fgrp = tid >> 7;           // 0..3
    const int f4   = (tid & 127) * 4;
    float4 c[QT];
    #pragma unroll
    for (int q = 0; q < QT; ++q) c[q] = make_float4(0.f, 0.f, 0.f, 0.f);
    const float* eb = enc + (size_t)b * TE * DE + f4;
    const int tb = fgrp * 64;
    #pragma unroll 4
    for (int t = tb; t < tb + 64; ++t) {
      float4 ee = *(const float4*)(eb + (size_t)t * DE);
      #pragma unroll
      for (int q = 0; q < QT; ++q) {
        float w = s_sc[q][t];
        c[q].x = fmaf(w, ee.x, c[q].x);
        c[q].y = fmaf(w, ee.y, c[q].y);
        c[q].z = fmaf(w, ee.z, c[q].z);
        c[q].w = fmaf(w, ee.w, c[q].w);
      }
    }
    if (fgrp > 0) {
      #pragma unroll
      for (int q = 0; q < QT; ++q) *(float4*)&red[fgrp - 1][q][f4] = c[q];
    }
    __syncthreads();
    if (fgrp == 0) {
      #pragma unroll
      for (int q = 0; q < QT; ++q) {
        float4 r1 = *(const float4*)&red[0][q][f4];
        float4 r2 = *(const float4*)&red[1][q][f4];
        float4 r3 = *(const float4*)&red[2][q][f4];
        c[q].x += (r1.x + r2.x) + r3.x;
        c[q].y += (r1.y + r2.y) + r3.y;
        c[q].z += (r1.z + r2.z) + r3.z;
        c[q].w += (r1.w + r2.w) + r3.w;
        *(float4*)(out_c + (size_t)(b * TD + q0 + q) * DE + f4) = c[q];
      }
    }
  }
}

extern "C" void kernel_launch(void* const* d_in, const int* in_sizes, int n_in,
                              void* d_out, int out_size, void* d_ws, size_t ws_size,
                              hipStream_t stream) {
  const float* enc = (const float*)d_in[0];
  const float* dec = (const float*)d_in[1];
  const float* Wa  = (const float*)d_in[2];
  const float* Ua  = (const float*)d_in[3];
  const float* Va  = (const float*)d_in[4];
  float* out_c = (float*)d_out;
  float* out_e = out_c + (size_t)NB * TD * DE;          // c first, then e

  // workspace layout (10 MB):
  float* ws = (float*)d_ws;                             // ew = e^{2Ws}: 4 MB
  float* uh = ws + 1048576;                             // eu = e^{2Uh}: 4 MB
  unsigned short* BHw = (unsigned short*)(uh + 1048576);// 0.5 MB each
  unsigned short* BLw = BHw + 262144;
  unsigned short* BHu = BLw + 262144;
  unsigned short* BLu = BHu + 262144;

  convB<<<dim3(16, 16, 2), dim3(256), 0, stream>>>(Wa, BHw, BLw, Ua, BHu, BLu);
  gemm_mfma<<<dim3(1024), dim3(256), 0, stream>>>(
      enc, BHw, BLw, ws, dec, BHu, BLu, uh);
  attn<<<dim3(NB * (TD / QT)), dim3(512), 0, stream>>>(
      ws, uh, enc, Va, out_c, out_e);
}

// Round 11
// 69.957 us; speedup vs baseline: 1.4369x; 1.0186x over previous
//
#include <hip/hip_runtime.h>

#define NB 8
#define TE 256
#define TD 256
#define DE 512
#define QT 4

// K2 = 2*log2(e): exp2(K2*x) = e^{2x}; tanh(x) = 1 - 2/(e^{2x}+1).
#define K2SCALE 2.8853900817779268f

typedef short bf16x8 __attribute__((ext_vector_type(8)));           // 8 bf16 (4 VGPR)
typedef float f32x4 __attribute__((ext_vector_type(4)));            // MFMA acc
typedef unsigned short u16x8 __attribute__((ext_vector_type(8)));   // 16 B

// round-to-nearest-even f32 -> bf16
static __device__ __forceinline__ unsigned short f2bf(float x) {
  unsigned int u = __float_as_uint(x);
  u += 0x7fffu + ((u >> 16) & 1u);
  return (unsigned short)(u >> 16);
}

// ---- prep: split A (f32->hi/lo bf16) and B (transpose+split) into PACKED ------
// fragment order: frag-tile = 16 rows x 32 k; lane = g*16 + r16 holds
// row=r16, k=g*8..g*8+7 (exactly the mfma_f32_16x16x32_bf16 A/B load pattern).
// A packed:  [z][m_tile 0..127][k_tile 0..15][lane 0..63][8]  (4 MB hi + 4 MB lo)
// B packed:  [z][n_tile 0..31 ][k_tile 0..15][lane 0..63][8]  (1 MB hi/lo total)
// Blocks 0..1023: A-part (z = b>>9, 4 rows/block, coalesced reads).
// Blocks 1024..1535: B-part (32x32 W-tile, gather-transpose, 128 active thr).
__global__ __launch_bounds__(256) void prep(
    const float* __restrict__ enc, const float* __restrict__ dec,
    const float* __restrict__ Wa,  const float* __restrict__ Ua,
    unsigned short* __restrict__ AHp, unsigned short* __restrict__ ALp,
    unsigned short* __restrict__ BHp, unsigned short* __restrict__ BLp)
{
  const int b = blockIdx.x;
  const int t = threadIdx.x;
  if (b < 1024) {
    const int z  = b >> 9;
    const int rb = b & 511;
    const int row = rb * 4 + (t >> 6);       // 0..2047
    const int tk  = t & 63;
    const int k0  = tk * 8;
    const float* src = (z ? dec : enc) + (size_t)row * DE + k0;
    float4 x0 = *(const float4*)(src);
    float4 x1 = *(const float4*)(src + 4);
    float xs[8] = {x0.x, x0.y, x0.z, x0.w, x1.x, x1.y, x1.z, x1.w};
    u16x8 h, l;
    #pragma unroll
    for (int j = 0; j < 8; ++j) {
      unsigned short hh = f2bf(xs[j]);
      float hf = __uint_as_float((unsigned int)hh << 16);
      h[j] = hh;
      l[j] = f2bf(xs[j] - hf);
    }
    const int m_tile = row >> 4, r16 = row & 15;
    const int k_tile = tk >> 2, g = tk & 3;
    const int lane = g * 16 + r16;
    const size_t dst = (((size_t)(z * 128 + m_tile) * 16 + k_tile) * 64 + lane) * 8;
    *(u16x8*)(AHp + dst) = h;
    *(u16x8*)(ALp + dst) = l;
  } else {
    if (t >= 128) return;
    const int idx = b - 1024;                // 0..511
    const int z  = idx >> 8;
    const int ti = idx & 255;
    const int k0 = (ti >> 4) * 32, n0 = (ti & 15) * 32;
    const int sub = t >> 6, l = t & 63;
    const int r16 = l & 15, g = l >> 4;
    const int n = n0 + sub * 16 + r16;
    const float* W = z ? Ua : Wa;
    u16x8 h, lo;
    #pragma unroll
    for (int e = 0; e < 8; ++e) {
      float x = W[(size_t)(k0 + g * 8 + e) * DE + n];
      unsigned short hh = f2bf(x);
      float hf = __uint_as_float((unsigned int)hh << 16);
      h[e] = hh;
      lo[e] = f2bf(x - hf);
    }
    const int n_tile = (ti & 15) * 2 + sub;  // 0..31
    const int k_tile = ti >> 4;
    const size_t dst = (((size_t)(z * 32 + n_tile) * 16 + k_tile) * 64 + l) * 8;
    *(u16x8*)(BHp + dst) = h;
    *(u16x8*)(BLp + dst) = lo;
  }
}

// ---- gemm_pk: C = exp2(K2 * A@B) from packed operands ------------------------
// NO LDS, NO barriers: each wave owns an independent 32x32 output tile (2x2
// 16x16 frags x 3 split terms = 12 MFMA/kt); per kt it issues 8 fully-coalesced
// 16B/lane fragment loads (L2-hot) with 1-step register prefetch. Block = 2x2
// wave-tiles (L1 frag sharing). grid 512: per-XCD slice (z, 8 m-groups) keeps
// the XCD working set at 2 MB < 4 MB L2 (blk&7=XCD proven by R7 FETCH drop).
__global__ __launch_bounds__(256) void gemm_pk(
    const unsigned short* __restrict__ AH, const unsigned short* __restrict__ AL,
    const unsigned short* __restrict__ BH, const unsigned short* __restrict__ BL,
    float* __restrict__ C0, float* __restrict__ C1)
{
  const int blk = blockIdx.x;
  const int xcd = blk & 7;
  const int i   = blk >> 3;                  // 0..63
  const int z   = xcd >> 2;
  const int mg  = (xcd & 3) * 8 + (i >> 3);  // 0..31
  const int ng  = i & 7;                     // 0..7
  const int w   = threadIdx.x >> 6;
  const int lane = threadIdx.x & 63;
  const int mt2 = mg * 2 + (w >> 1);         // 0..63  (32-row wave-tile)
  const int nt2 = ng * 2 + (w & 1);          // 0..15  (32-col wave-tile)
  const int mtile0 = mt2 * 2, ntile0 = nt2 * 2;

  const unsigned short* pah = AH + ((size_t)(z * 128 + mtile0) * 16) * 512 + lane * 8;
  const unsigned short* pal = AL + ((size_t)(z * 128 + mtile0) * 16) * 512 + lane * 8;
  const unsigned short* pbh = BH + ((size_t)(z * 32 + ntile0) * 16) * 512 + lane * 8;
  const unsigned short* pbl = BL + ((size_t)(z * 32 + ntile0) * 16) * 512 + lane * 8;
  // second frag-tile of the pair is +16 k_tiles = +8192 ushorts

  f32x4 m00 = {0,0,0,0}, m01 = {0,0,0,0}, m10 = {0,0,0,0}, m11 = {0,0,0,0};
  f32x4 e00 = {0,0,0,0}, e01 = {0,0,0,0}, e10 = {0,0,0,0}, e11 = {0,0,0,0};

  bf16x8 ah0 = *(const bf16x8*)(pah);
  bf16x8 ah1 = *(const bf16x8*)(pah + 8192);
  bf16x8 al0 = *(const bf16x8*)(pal);
  bf16x8 al1 = *(const bf16x8*)(pal + 8192);
  bf16x8 bh0 = *(const bf16x8*)(pbh);
  bf16x8 bh1 = *(const bf16x8*)(pbh + 8192);
  bf16x8 bl0 = *(const bf16x8*)(pbl);
  bf16x8 bl1 = *(const bf16x8*)(pbl + 8192);

  for (int kt = 0; kt < 16; ++kt) {
    bf16x8 cah0 = ah0, cah1 = ah1, cal0 = al0, cal1 = al1;
    bf16x8 cbh0 = bh0, cbh1 = bh1, cbl0 = bl0, cbl1 = bl1;
    if (kt < 15) {                           // register prefetch, no barrier
      pah += 512; pal += 512; pbh += 512; pbl += 512;
      ah0 = *(const bf16x8*)(pah);
      ah1 = *(const bf16x8*)(pah + 8192);
      al0 = *(const bf16x8*)(pal);
      al1 = *(const bf16x8*)(pal + 8192);
      bh0 = *(const bf16x8*)(pbh);
      bh1 = *(const bf16x8*)(pbh + 8192);
      bl0 = *(const bf16x8*)(pbl);
      bl1 = *(const bf16x8*)(pbl + 8192);
    }
    m00 = __builtin_amdgcn_mfma_f32_16x16x32_bf16(cah0, cbh0, m00, 0, 0, 0);
    m01 = __builtin_amdgcn_mfma_f32_16x16x32_bf16(cah0, cbh1, m01, 0, 0, 0);
    m10 = __builtin_amdgcn_mfma_f32_16x16x32_bf16(cah1, cbh0, m10, 0, 0, 0);
    m11 = __builtin_amdgcn_mfma_f32_16x16x32_bf16(cah1, cbh1, m11, 0, 0, 0);
    e00 = __builtin_amdgcn_mfma_f32_16x16x32_bf16(cal0, cbh0, e00, 0, 0, 0);
    e00 = __builtin_amdgcn_mfma_f32_16x16x32_bf16(cah0, cbl0, e00, 0, 0, 0);
    e01 = __builtin_amdgcn_mfma_f32_16x16x32_bf16(cal0, cbh1, e01, 0, 0, 0);
    e01 = __builtin_amdgcn_mfma_f32_16x16x32_bf16(cah0, cbl1, e01, 0, 0, 0);
    e10 = __builtin_amdgcn_mfma_f32_16x16x32_bf16(cal1, cbh0, e10, 0, 0, 0);
    e10 = __builtin_amdgcn_mfma_f32_16x16x32_bf16(cah1, cbl0, e10, 0, 0, 0);
    e11 = __builtin_amdgcn_mfma_f32_16x16x32_bf16(cal1, cbh1, e11, 0, 0, 0);
    e11 = __builtin_amdgcn_mfma_f32_16x16x32_bf16(cah1, cbl1, e11, 0, 0, 0);
  }

  float* C = z ? C1 : C0;
  const int g = lane >> 4, r16 = lane & 15;
  f32x4 vm[2][2] = {{m00, m01}, {m10, m11}};
  f32x4 ve[2][2] = {{e00, e01}, {e10, e11}};
  #pragma unroll
  for (int mt = 0; mt < 2; ++mt)
    #pragma unroll
    for (int nt = 0; nt < 2; ++nt)
      #pragma unroll
      for (int jj = 0; jj < 4; ++jj) {
        float vsum = vm[mt][nt][jj] + ve[mt][nt][jj];
        int row = (mtile0 + mt) * 16 + g * 4 + jj;
        int col = (ntile0 + nt) * 16 + r16;
        C[(size_t)row * 512 + col] = __builtin_amdgcn_exp2f(vsum * K2SCALE);
      }
}

// ---------------- fused scores + softmax + context (R7-exact, proven ~48us) ----
__global__ __launch_bounds__(512) void attn(
    const float* __restrict__ ws, const float* __restrict__ uh,
    const float* __restrict__ enc, const float* __restrict__ va,
    float* __restrict__ out_c, float* __restrict__ out_e)
{
  const int tid  = threadIdx.x;
  const int wave = tid >> 6;
  const int lane = tid & 63;
  const int b  = blockIdx.x & 7;           // XCD-locality: batch <-> XCD
  const int q0 = (blockIdx.x >> 3) * QT;
  __shared__ float s_sc[QT][TE];           // 4 KB
  __shared__ float red[3][QT][DE];         // 24 KB, context partials
  const int fbase = lane * 8;              // lane owns 8 contiguous f

  float4 v0 = *(const float4*)(va + fbase);
  float4 v1 = *(const float4*)(va + fbase + 4);
  float v[8] = {v0.x, v0.y, v0.z, v0.w, v1.x, v1.y, v1.z, v1.w};

  float eu[QT][8];
  #pragma unroll
  for (int q = 0; q < QT; ++q) {
    const float* up = uh + (size_t)(b * TD + q0 + q) * DE + fbase;
    float4 u0 = *(const float4*)(up);
    float4 u1 = *(const float4*)(up + 4);
    eu[q][0] = u0.x; eu[q][1] = u0.y; eu[q][2] = u0.z; eu[q][3] = u0.w;
    eu[q][4] = u1.x; eu[q][5] = u1.y; eu[q][6] = u1.z; eu[q][7] = u1.w;
  }

  // ---- scores: wave owns t in [wave*32, wave*32+32), 1-deep prefetch on ws ----
  const int t0 = wave * 32;
  const float* wp = ws + (size_t)(b * TE + t0) * DE + fbase;
  float4 w0 = *(const float4*)(wp);
  float4 w1 = *(const float4*)(wp + 4);
  for (int t = t0; t < t0 + 32; ++t) {
    float cw[8] = {w0.x, w0.y, w0.z, w0.w, w1.x, w1.y, w1.z, w1.w};
    // prefetch next row; last iteration reads one row past (lands in uh[0],
    // still inside the same workspace allocation) and is unused.
    wp += DE;
    w0 = *(const float4*)(wp);
    w1 = *(const float4*)(wp + 4);
    float a[QT];
    #pragma unroll
    for (int q = 0; q < QT; ++q) {
      float A0 = fmaf(cw[0], eu[q][0], 1.f);
      float A1 = fmaf(cw[1], eu[q][1], 1.f);
      float A2 = fmaf(cw[2], eu[q][2], 1.f);
      float A3 = fmaf(cw[3], eu[q][3], 1.f);
      float B0 = fmaf(cw[4], eu[q][4], 1.f);
      float B1 = fmaf(cw[5], eu[q][5], 1.f);
      float B2 = fmaf(cw[6], eu[q][6], 1.f);
      float B3 = fmaf(cw[7], eu[q][7], 1.f);
      float n1 = fmaf(v[1], A0, v[0] * A1);
      float d1 = A0 * A1;
      float n2 = fmaf(v[3], A2, v[2] * A3);
      float d2 = A2 * A3;
      float N1 = fmaf(n2, d1, n1 * d2);
      float D1 = d1 * d2;
      float n3 = fmaf(v[5], B0, v[4] * B1);
      float d3 = B0 * B1;
      float n4 = fmaf(v[7], B2, v[6] * B3);
      float d4 = B2 * B3;
      float N2 = fmaf(n4, d3, n3 * d4);
      float D2 = d3 * d4;
      float s = N1 * __builtin_amdgcn_rcpf(D1);
      a[q] = fmaf(N2, __builtin_amdgcn_rcpf(D2), s);
    }
    {
      const bool h1 = lane & 1;
      float m0 = h1 ? a[1] : a[0], o0 = h1 ? a[0] : a[1];
      float m1 = h1 ? a[3] : a[2], o1 = h1 ? a[2] : a[3];
      float r0 = m0 + __shfl_xor(o0, 1, 64);
      float r1 = m1 + __shfl_xor(o1, 1, 64);
      const bool h2 = lane & 2;
      float mm = h2 ? r1 : r0, oo = h2 ? r0 : r1;
      float r = mm + __shfl_xor(oo, 2, 64);
      r += __shfl_xor(r, 4, 64);
      r += __shfl_xor(r, 8, 64);
      r += __shfl_xor(r, 16, 64);
      r += __shfl_xor(r, 32, 64);
      if (lane < QT) s_sc[lane][t] = -2.f * r;
    }
  }
  __syncthreads();

  // ---- softmax: waves 0..3 handle row = wave; waves 4..7 wait ----
  if (wave < QT) {
    const int r = wave;
    float x[4];
    #pragma unroll
    for (int i = 0; i < 4; ++i) x[i] = s_sc[r][lane + 64 * i];
    float m = fmaxf(fmaxf(x[0], x[1]), fmaxf(x[2], x[3]));
    #pragma unroll
    for (int off = 32; off >= 1; off >>= 1) m = fmaxf(m, __shfl_xor(m, off, 64));
    const float L2E = 1.4426950408889634f;
    float ssum = 0.f;
    #pragma unroll
    for (int i = 0; i < 4; ++i) { x[i] = __builtin_amdgcn_exp2f((x[i] - m) * L2E); ssum += x[i]; }
    #pragma unroll
    for (int off = 32; off >= 1; off >>= 1) ssum += __shfl_xor(ssum, off, 64);
    float inv = 1.f / ssum;
    float* oe = out_e + (size_t)(b * TD + q0 + r) * TE;
    #pragma unroll
    for (int i = 0; i < 4; ++i) {
      float e = x[i] * inv;
      s_sc[r][lane + 64 * i] = e;
      oe[lane + 64 * i] = e;
    }
  }
  __syncthreads();

  // ---- context: c[q][f4..f4+3] = sum_t e[q][t]*enc[b][t][f4..f4+3] ----
  {
    const int fgrp = tid >> 7;           // 0..3
    const int f4   = (tid & 127) * 4;
    float4 c[QT];
    #pragma unroll
    for (int q = 0; q < QT; ++q) c[q] = make_float4(0.f, 0.f, 0.f, 0.f);
    const float* eb = enc + (size_t)b * TE * DE + f4;
    const int tb = fgrp * 64;
    #pragma unroll 4
    for (int t = tb; t < tb + 64; ++t) {
      float4 ee = *(const float4*)(eb + (size_t)t * DE);
      #pragma unroll
      for (int q = 0; q < QT; ++q) {
        float w = s_sc[q][t];
        c[q].x = fmaf(w, ee.x, c[q].x);
        c[q].y = fmaf(w, ee.y, c[q].y);
        c[q].z = fmaf(w, ee.z, c[q].z);
        c[q].w = fmaf(w, ee.w, c[q].w);
      }
    }
    if (fgrp > 0) {
      #pragma unroll
      for (int q = 0; q < QT; ++q) *(float4*)&red[fgrp - 1][q][f4] = c[q];
    }
    __syncthreads();
    if (fgrp == 0) {
      #pragma unroll
      for (int q = 0; q < QT; ++q) {
        float4 r1 = *(const float4*)&red[0][q][f4];
        float4 r2 = *(const float4*)&red[1][q][f4];
        float4 r3 = *(const float4*)&red[2][q][f4];
        c[q].x += (r1.x + r2.x) + r3.x;
        c[q].y += (r1.y + r2.y) + r3.y;
        c[q].z += (r1.z + r2.z) + r3.z;
        c[q].w += (r1.w + r2.w) + r3.w;
        *(float4*)(out_c + (size_t)(b * TD + q0 + q) * DE + f4) = c[q];
      }
    }
  }
}

extern "C" void kernel_launch(void* const* d_in, const int* in_sizes, int n_in,
                              void* d_out, int out_size, void* d_ws, size_t ws_size,
                              hipStream_t stream) {
  const float* enc = (const float*)d_in[0];
  const float* dec = (const float*)d_in[1];
  const float* Wa  = (const float*)d_in[2];
  const float* Ua  = (const float*)d_in[3];
  const float* Va  = (const float*)d_in[4];
  float* out_c = (float*)d_out;
  float* out_e = out_c + (size_t)NB * TD * DE;          // c first, then e

  // workspace layout (18 MB):
  float* ws = (float*)d_ws;                             // ew = e^{2Ws}: 4 MB
  float* uh = ws + 1048576;                             // eu = e^{2Uh}: 4 MB
  unsigned short* AHp = (unsigned short*)(uh + 1048576);// packed A hi: 4 MB
  unsigned short* ALp = AHp + 2097152;                  // packed A lo: 4 MB
  unsigned short* BHp = ALp + 2097152;                  // packed B hi: 1 MB
  unsigned short* BLp = BHp + 524288;                   // packed B lo: 1 MB

  prep<<<dim3(1536), dim3(256), 0, stream>>>(enc, dec, Wa, Ua, AHp, ALp, BHp, BLp);
  gemm_pk<<<dim3(512), dim3(256), 0, stream>>>(AHp, ALp, BHp, BLp, ws, uh);
  attn<<<dim3(NB * (TD / QT)), dim3(512), 0, stream>>>(
      ws, uh, enc, Va, out_c, out_e);
}

// Round 12
// 68.662 us; speedup vs baseline: 1.4640x; 1.0189x over previous
//
#include <hip/hip_runtime.h>

#define NB 8
#define TE 256
#define TD 256
#define DE 512
#define QT 4

// K2 = 2*log2(e): exp2(K2*x) = e^{2x}; tanh(x) = 1 - 2/(e^{2x}+1).
#define K2SCALE 2.8853900817779268f

typedef short bf16x8 __attribute__((ext_vector_type(8)));           // 8 bf16 (4 VGPR)
typedef float f32x4 __attribute__((ext_vector_type(4)));            // MFMA acc
typedef unsigned short u16x8 __attribute__((ext_vector_type(8)));   // 16 B staging

// round-to-nearest-even f32 -> bf16
static __device__ __forceinline__ unsigned short f2bf(float x) {
  unsigned int u = __float_as_uint(x);
  u += 0x7fffu + ((u >> 16) & 1u);
  return (unsigned short)(u >> 16);
}

// split f32 -> hi (ROUNDED bf16) + lo (rounded residual).
static __device__ __forceinline__ void split8(
    const float4& x0, const float4& x1, u16x8& h, u16x8& l) {
  float xs[8] = {x0.x, x0.y, x0.z, x0.w, x1.x, x1.y, x1.z, x1.w};
  #pragma unroll
  for (int j = 0; j < 8; ++j) {
    unsigned short hh = f2bf(xs[j]);
    float hf = __uint_as_float((unsigned int)hh << 16);
    h[j] = hh;
    l[j] = f2bf(xs[j] - hf);
  }
}

// ---- convB: W [512x512] f32 -> TRANSPOSED hi/lo bf16 BT[n][k] (32x32 tiles) ----
// grid (16, 16, 2), 256 thr.  (R6-exact: chain minimum 17.1us)
__global__ __launch_bounds__(256) void convB(
    const float* __restrict__ w0, unsigned short* __restrict__ h0, unsigned short* __restrict__ l0,
    const float* __restrict__ w1, unsigned short* __restrict__ h1, unsigned short* __restrict__ l1)
{
  const float* W = blockIdx.z ? w1 : w0;
  unsigned short* H = blockIdx.z ? h1 : h0;
  unsigned short* L = blockIdx.z ? l1 : l0;
  __shared__ unsigned short sh[32][33], sl[32][33];
  const int t = threadIdx.x;
  const int k0 = blockIdx.y * 32, n0 = blockIdx.x * 32;
  const int r = t >> 3, c = (t & 7) * 4;
  float4 x = *(const float4*)(W + (size_t)(k0 + r) * DE + n0 + c);
  float xs[4] = {x.x, x.y, x.z, x.w};
  #pragma unroll
  for (int j = 0; j < 4; ++j) {
    unsigned short hh = f2bf(xs[j]);
    float hf = __uint_as_float((unsigned int)hh << 16);
    sh[r][c + j] = hh;
    sl[r][c + j] = f2bf(xs[j] - hf);
  }
  __syncthreads();
  ushort4 oh, ol;
  oh.x = sh[c + 0][r]; oh.y = sh[c + 1][r]; oh.z = sh[c + 2][r]; oh.w = sh[c + 3][r];
  ol.x = sl[c + 0][r]; ol.y = sl[c + 1][r]; ol.z = sl[c + 2][r]; ol.w = sl[c + 3][r];
  *(ushort4*)(H + (size_t)(n0 + r) * DE + k0 + c) = oh;
  *(ushort4*)(L + (size_t)(n0 + r) * DE + k0 + c) = ol;
}

// ---- gemm_mfma: C = exp2(K2 * A@B), A f32 split in-register, dbuf LDS ---------
// R6-exact: BM=64 BN=64 KT=32, 256 thr (4 waves 2x2), wave-tile 32x32,
// grid (8, 32, 2) 2D decode (the XCD-clustered 1D decode of R7 was 4us SLOWER).
__global__ __launch_bounds__(256) void gemm_mfma(
    const float* __restrict__ A0,
    const unsigned short* __restrict__ BH0, const unsigned short* __restrict__ BL0,
    float* __restrict__ C0,
    const float* __restrict__ A1,
    const unsigned short* __restrict__ BH1, const unsigned short* __restrict__ BL1,
    float* __restrict__ C1)
{
  const float*          A  = blockIdx.z ? A1  : A0;
  const unsigned short* BH = blockIdx.z ? BH1 : BH0;
  const unsigned short* BL = blockIdx.z ? BL1 : BL0;
  float*                C  = blockIdx.z ? C1  : C0;
  const int tid  = threadIdx.x;
  const int lane = tid & 63;
  const int wave = tid >> 6;
  const int wm = wave >> 1, wn = wave & 1;
  const int g = lane >> 4, r16 = lane & 15;
  const int m0 = blockIdx.y * 64, n0 = blockIdx.x * 64;
  __shared__ __align__(16) unsigned short Ah[2][64][40], Al[2][64][40];
  __shared__ __align__(16) unsigned short Bh[2][64][40], Bl[2][64][40];
  const int arow = tid >> 2;            // 0..63
  const int apart = (tid & 3) * 8;      // 8-elem (16 B) piece of a 32-elem row

  float4 a00, a01;
  u16x8 pb, plb;
#define LOADTILE(KT) do {                                                   \
    const size_t ko = (size_t)(KT) * 32 + apart;                            \
    const float* pa_ = A + (size_t)(m0 + arow) * 512 + ko;                  \
    a00 = *(const float4*)pa_;  a01 = *(const float4*)(pa_ + 4);            \
    pb  = *(const u16x8*)(BH + (size_t)(n0 + arow) * 512 + ko);             \
    plb = *(const u16x8*)(BL + (size_t)(n0 + arow) * 512 + ko);             \
  } while (0)
#define STORETILE(BUF) do {                                                 \
    u16x8 h0_, l0_;                                                         \
    split8(a00, a01, h0_, l0_);                                             \
    *(u16x8*)&Ah[BUF][arow][apart] = h0_;                                   \
    *(u16x8*)&Al[BUF][arow][apart] = l0_;                                   \
    *(u16x8*)&Bh[BUF][arow][apart] = pb;                                    \
    *(u16x8*)&Bl[BUF][arow][apart] = plb;                                   \
  } while (0)

  f32x4 accm[2][2], acce[2][2];
  #pragma unroll
  for (int mt = 0; mt < 2; ++mt)
    #pragma unroll
    for (int nt = 0; nt < 2; ++nt) {
      accm[mt][nt] = (f32x4){0.f, 0.f, 0.f, 0.f};
      acce[mt][nt] = (f32x4){0.f, 0.f, 0.f, 0.f};
    }

  LOADTILE(0);
  STORETILE(0);
  __syncthreads();

  for (int kt = 0; kt < 16; ++kt) {
    const int cur = kt & 1;
    if (kt + 1 < 16) LOADTILE(kt + 1);  // issue early; hides under compute
    bf16x8 ah[2], al[2], bh[2], bl[2];
    #pragma unroll
    for (int mt = 0; mt < 2; ++mt) {
      ah[mt] = *(const bf16x8*)&Ah[cur][wm * 32 + mt * 16 + r16][g * 8];
      al[mt] = *(const bf16x8*)&Al[cur][wm * 32 + mt * 16 + r16][g * 8];
    }
    #pragma unroll
    for (int nt = 0; nt < 2; ++nt) {
      bh[nt] = *(const bf16x8*)&Bh[cur][wn * 32 + nt * 16 + r16][g * 8];
      bl[nt] = *(const bf16x8*)&Bl[cur][wn * 32 + nt * 16 + r16][g * 8];
    }
    #pragma unroll
    for (int mt = 0; mt < 2; ++mt)
      #pragma unroll
      for (int nt = 0; nt < 2; ++nt) {
        accm[mt][nt] = __builtin_amdgcn_mfma_f32_16x16x32_bf16(ah[mt], bh[nt], accm[mt][nt], 0, 0, 0);
        acce[mt][nt] = __builtin_amdgcn_mfma_f32_16x16x32_bf16(al[mt], bh[nt], acce[mt][nt], 0, 0, 0);
        acce[mt][nt] = __builtin_amdgcn_mfma_f32_16x16x32_bf16(ah[mt], bl[nt], acce[mt][nt], 0, 0, 0);
      }
    if (kt + 1 < 16) STORETILE(cur ^ 1);  // other buffer: no hazard
    __syncthreads();                       // single barrier per k-tile
  }
#undef LOADTILE
#undef STORETILE

  #pragma unroll
  for (int mt = 0; mt < 2; ++mt)
    #pragma unroll
    for (int nt = 0; nt < 2; ++nt)
      #pragma unroll
      for (int jj = 0; jj < 4; ++jj) {
        float vsum = accm[mt][nt][jj] + acce[mt][nt][jj];
        int row = m0 + wm * 32 + mt * 16 + g * 4 + jj;
        int col = n0 + wn * 32 + nt * 16 + r16;
        C[(size_t)row * 512 + col] = __builtin_amdgcn_exp2f(vsum * K2SCALE);
      }
}

// ---------------- fused scores + softmax + context -----------------------------
// R7 structure, ONE change: __launch_bounds__(512, 4) -> VGPR cap 128 (was 44).
// At 44 VGPR the compiler could not keep eu[4][8]+v[8]+cw[8] (~70 live regs)
// resident and re-loaded eu inside every t-iteration (~32 hidden L1 loads/t) --
// the 2x gap between the instruction model (~20us) and measured VALU busy time
// (~35us). Grid gives 2 blocks/CU = 4 waves/SIMD either way; the 8-wave VGPR
// target the compiler was optimizing for is unreachable.
__global__ __launch_bounds__(512, 4) void attn(
    const float* __restrict__ ws, const float* __restrict__ uh,
    const float* __restrict__ enc, const float* __restrict__ va,
    float* __restrict__ out_c, float* __restrict__ out_e)
{
  const int tid  = threadIdx.x;
  const int wave = tid >> 6;
  const int lane = tid & 63;
  const int b  = blockIdx.x & 7;           // XCD-locality: batch <-> XCD
  const int q0 = (blockIdx.x >> 3) * QT;
  __shared__ float s_sc[QT][TE];           // 4 KB
  __shared__ float red[3][QT][DE];         // 24 KB, context partials
  const int fbase = lane * 8;              // lane owns 8 contiguous f

  float4 v0 = *(const float4*)(va + fbase);
  float4 v1 = *(const float4*)(va + fbase + 4);
  float v[8] = {v0.x, v0.y, v0.z, v0.w, v1.x, v1.y, v1.z, v1.w};

  float eu[QT][8];
  #pragma unroll
  for (int q = 0; q < QT; ++q) {
    const float* up = uh + (size_t)(b * TD + q0 + q) * DE + fbase;
    float4 u0 = *(const float4*)(up);
    float4 u1 = *(const float4*)(up + 4);
    eu[q][0] = u0.x; eu[q][1] = u0.y; eu[q][2] = u0.z; eu[q][3] = u0.w;
    eu[q][4] = u1.x; eu[q][5] = u1.y; eu[q][6] = u1.z; eu[q][7] = u1.w;
  }

  // ---- scores: wave owns t in [wave*32, wave*32+32), 1-deep prefetch on ws ----
  const int t0 = wave * 32;
  const float* wp = ws + (size_t)(b * TE + t0) * DE + fbase;
  float4 w0 = *(const float4*)(wp);
  float4 w1 = *(const float4*)(wp + 4);
  for (int t = t0; t < t0 + 32; ++t) {
    float cw[8] = {w0.x, w0.y, w0.z, w0.w, w1.x, w1.y, w1.z, w1.w};
    // prefetch next row; last iteration reads one row past (lands in uh[0],
    // still inside the same workspace allocation) and is unused.
    wp += DE;
    w0 = *(const float4*)(wp);
    w1 = *(const float4*)(wp + 4);
    float a[QT];
    #pragma unroll
    for (int q = 0; q < QT; ++q) {
      float A0 = fmaf(cw[0], eu[q][0], 1.f);
      float A1 = fmaf(cw[1], eu[q][1], 1.f);
      float A2 = fmaf(cw[2], eu[q][2], 1.f);
      float A3 = fmaf(cw[3], eu[q][3], 1.f);
      float B0 = fmaf(cw[4], eu[q][4], 1.f);
      float B1 = fmaf(cw[5], eu[q][5], 1.f);
      float B2 = fmaf(cw[6], eu[q][6], 1.f);
      float B3 = fmaf(cw[7], eu[q][7], 1.f);
      float n1 = fmaf(v[1], A0, v[0] * A1);
      float d1 = A0 * A1;
      float n2 = fmaf(v[3], A2, v[2] * A3);
      float d2 = A2 * A3;
      float N1 = fmaf(n2, d1, n1 * d2);
      float D1 = d1 * d2;
      float n3 = fmaf(v[5], B0, v[4] * B1);
      float d3 = B0 * B1;
      float n4 = fmaf(v[7], B2, v[6] * B3);
      float d4 = B2 * B3;
      float N2 = fmaf(n4, d3, n3 * d4);
      float D2 = d3 * d4;
      float s = N1 * __builtin_amdgcn_rcpf(D1);
      a[q] = fmaf(N2, __builtin_amdgcn_rcpf(D2), s);
    }
    {
      const bool h1 = lane & 1;
      float m0 = h1 ? a[1] : a[0], o0 = h1 ? a[0] : a[1];
      float m1 = h1 ? a[3] : a[2], o1 = h1 ? a[2] : a[3];
      float r0 = m0 + __shfl_xor(o0, 1, 64);
      float r1 = m1 + __shfl_xor(o1, 1, 64);
      const bool h2 = lane & 2;
      float mm = h2 ? r1 : r0, oo = h2 ? r0 : r1;
      float r = mm + __shfl_xor(oo, 2, 64);
      r += __shfl_xor(r, 4, 64);
      r += __shfl_xor(r, 8, 64);
      r += __shfl_xor(r, 16, 64);
      r += __shfl_xor(r, 32, 64);
      if (lane < QT) s_sc[lane][t] = -2.f * r;
    }
  }
  __syncthreads();

  // ---- softmax: waves 0..3 handle row = wave; waves 4..7 wait ----
  if (wave < QT) {
    const int r = wave;
    float x[4];
    #pragma unroll
    for (int i = 0; i < 4; ++i) x[i] = s_sc[r][lane + 64 * i];
    float m = fmaxf(fmaxf(x[0], x[1]), fmaxf(x[2], x[3]));
    #pragma unroll
    for (int off = 32; off >= 1; off >>= 1) m = fmaxf(m, __shfl_xor(m, off, 64));
    const float L2E = 1.4426950408889634f;
    float ssum = 0.f;
    #pragma unroll
    for (int i = 0; i < 4; ++i) { x[i] = __builtin_amdgcn_exp2f((x[i] - m) * L2E); ssum += x[i]; }
    #pragma unroll
    for (int off = 32; off >= 1; off >>= 1) ssum += __shfl_xor(ssum, off, 64);
    float inv = 1.f / ssum;
    float* oe = out_e + (size_t)(b * TD + q0 + r) * TE;
    #pragma unroll
    for (int i = 0; i < 4; ++i) {
      float e = x[i] * inv;
      s_sc[r][lane + 64 * i] = e;
      oe[lane + 64 * i] = e;
    }
  }
  __syncthreads();

  // ---- context: c[q][f4..f4+3] = sum_t e[q][t]*enc[b][t][f4..f4+3] ----
  {
    const int fgrp = tid >> 7;           // 0..3
    const int f4   = (tid & 127) * 4;
    float4 c[QT];
    #pragma unroll
    for (int q = 0; q < QT; ++q) c[q] = make_float4(0.f, 0.f, 0.f, 0.f);
    const float* eb = enc + (size_t)b * TE * DE + f4;
    const int tb = fgrp * 64;
    #pragma unroll 4
    for (int t = tb; t < tb + 64; ++t) {
      float4 ee = *(const float4*)(eb + (size_t)t * DE);
      #pragma unroll
      for (int q = 0; q < QT; ++q) {
        float w = s_sc[q][t];
        c[q].x = fmaf(w, ee.x, c[q].x);
        c[q].y = fmaf(w, ee.y, c[q].y);
        c[q].z = fmaf(w, ee.z, c[q].z);
        c[q].w = fmaf(w, ee.w, c[q].w);
      }
    }
    if (fgrp > 0) {
      #pragma unroll
      for (int q = 0; q < QT; ++q) *(float4*)&red[fgrp - 1][q][f4] = c[q];
    }
    __syncthreads();
    if (fgrp == 0) {
      #pragma unroll
      for (int q = 0; q < QT; ++q) {
        float4 r1 = *(const float4*)&red[0][q][f4];
        float4 r2 = *(const float4*)&red[1][q][f4];
        float4 r3 = *(const float4*)&red[2][q][f4];
        c[q].x += (r1.x + r2.x) + r3.x;
        c[q].y += (r1.y + r2.y) + r3.y;
        c[q].z += (r1.z + r2.z) + r3.z;
        c[q].w += (r1.w + r2.w) + r3.w;
        *(float4*)(out_c + (size_t)(b * TD + q0 + q) * DE + f4) = c[q];
      }
    }
  }
}

extern "C" void kernel_launch(void* const* d_in, const int* in_sizes, int n_in,
                              void* d_out, int out_size, void* d_ws, size_t ws_size,
                              hipStream_t stream) {
  const float* enc = (const float*)d_in[0];
  const float* dec = (const float*)d_in[1];
  const float* Wa  = (const float*)d_in[2];
  const float* Ua  = (const float*)d_in[3];
  const float* Va  = (const float*)d_in[4];
  float* out_c = (float*)d_out;
  float* out_e = out_c + (size_t)NB * TD * DE;          // c first, then e

  // workspace layout (10 MB):
  float* ws = (float*)d_ws;                             // ew = e^{2Ws}: 4 MB
  float* uh = ws + 1048576;                             // eu = e^{2Uh}: 4 MB
  unsigned short* BHw = (unsigned short*)(uh + 1048576);// 0.5 MB each
  unsigned short* BLw = BHw + 262144;
  unsigned short* BHu = BLw + 262144;
  unsigned short* BLu = BHu + 262144;

  convB<<<dim3(16, 16, 2), dim3(256), 0, stream>>>(Wa, BHw, BLw, Ua, BHu, BLu);
  gemm_mfma<<<dim3(8, 32, 2), dim3(256), 0, stream>>>(
      enc, BHw, BLw, ws, dec, BHu, BLu, uh);
  attn<<<dim3(NB * (TD / QT)), dim3(512), 0, stream>>>(
      ws, uh, enc, Va, out_c, out_e);
}

// Round 13
// 68.125 us; speedup vs baseline: 1.4755x; 1.0079x over previous
//
#include <hip/hip_runtime.h>

#define NB 8
#define TE 256
#define TD 256
#define DE 512
#define QT 4

// K2 = 2*log2(e): exp2(K2*x) = e^{2x}; tanh(x) = 1 - 2/(e^{2x}+1).
#define K2SCALE 2.8853900817779268f

typedef short bf16x8 __attribute__((ext_vector_type(8)));           // 8 bf16 (4 VGPR)
typedef float f32x4 __attribute__((ext_vector_type(4)));            // MFMA acc
typedef unsigned short u16x8 __attribute__((ext_vector_type(8)));   // 16 B staging

// round-to-nearest-even f32 -> bf16
static __device__ __forceinline__ unsigned short f2bf(float x) {
  unsigned int u = __float_as_uint(x);
  u += 0x7fffu + ((u >> 16) & 1u);
  return (unsigned short)(u >> 16);
}

// split f32 -> hi (ROUNDED bf16) + lo (rounded residual).
static __device__ __forceinline__ void split8(
    const float4& x0, const float4& x1, u16x8& h, u16x8& l) {
  float xs[8] = {x0.x, x0.y, x0.z, x0.w, x1.x, x1.y, x1.z, x1.w};
  #pragma unroll
  for (int j = 0; j < 8; ++j) {
    unsigned short hh = f2bf(xs[j]);
    float hf = __uint_as_float((unsigned int)hh << 16);
    h[j] = hh;
    l[j] = f2bf(xs[j] - hf);
  }
}

// DPP cross-lane fetch at full VALU rate (no DS, no lgkmcnt chain).
// ctrl: 0xB1 = quad_perm[1,0,3,2] (xor1), 0x4E = quad_perm[2,3,0,1] (xor2),
//       0x124 = row_ror:4, 0x128 = row_ror:8 (within 16-lane row).
template <int CTRL>
static __device__ __forceinline__ float dpp_mov(float x) {
  return __int_as_float(__builtin_amdgcn_update_dpp(
      0, __float_as_int(x), CTRL, 0xf, 0xf, true));
}

// ---- convB: W [512x512] f32 -> TRANSPOSED hi/lo bf16 BT[n][k] (32x32 tiles) ----
// grid (16, 16, 2), 256 thr.  (R6-exact: chain minimum)
__global__ __launch_bounds__(256) void convB(
    const float* __restrict__ w0, unsigned short* __restrict__ h0, unsigned short* __restrict__ l0,
    const float* __restrict__ w1, unsigned short* __restrict__ h1, unsigned short* __restrict__ l1)
{
  const float* W = blockIdx.z ? w1 : w0;
  unsigned short* H = blockIdx.z ? h1 : h0;
  unsigned short* L = blockIdx.z ? l1 : l0;
  __shared__ unsigned short sh[32][33], sl[32][33];
  const int t = threadIdx.x;
  const int k0 = blockIdx.y * 32, n0 = blockIdx.x * 32;
  const int r = t >> 3, c = (t & 7) * 4;
  float4 x = *(const float4*)(W + (size_t)(k0 + r) * DE + n0 + c);
  float xs[4] = {x.x, x.y, x.z, x.w};
  #pragma unroll
  for (int j = 0; j < 4; ++j) {
    unsigned short hh = f2bf(xs[j]);
    float hf = __uint_as_float((unsigned int)hh << 16);
    sh[r][c + j] = hh;
    sl[r][c + j] = f2bf(xs[j] - hf);
  }
  __syncthreads();
  ushort4 oh, ol;
  oh.x = sh[c + 0][r]; oh.y = sh[c + 1][r]; oh.z = sh[c + 2][r]; oh.w = sh[c + 3][r];
  ol.x = sl[c + 0][r]; ol.y = sl[c + 1][r]; ol.z = sl[c + 2][r]; ol.w = sl[c + 3][r];
  *(ushort4*)(H + (size_t)(n0 + r) * DE + k0 + c) = oh;
  *(ushort4*)(L + (size_t)(n0 + r) * DE + k0 + c) = ol;
}

// ---- gemm_mfma: C = exp2(K2 * A@B), A f32 split in-register, dbuf LDS ---------
// R6-exact: BM=64 BN=64 KT=32, 256 thr (4 waves 2x2), wave-tile 32x32,
// grid (8, 32, 2) 2D decode.
__global__ __launch_bounds__(256) void gemm_mfma(
    const float* __restrict__ A0,
    const unsigned short* __restrict__ BH0, const unsigned short* __restrict__ BL0,
    float* __restrict__ C0,
    const float* __restrict__ A1,
    const unsigned short* __restrict__ BH1, const unsigned short* __restrict__ BL1,
    float* __restrict__ C1)
{
  const float*          A  = blockIdx.z ? A1  : A0;
  const unsigned short* BH = blockIdx.z ? BH1 : BH0;
  const unsigned short* BL = blockIdx.z ? BL1 : BL0;
  float*                C  = blockIdx.z ? C1  : C0;
  const int tid  = threadIdx.x;
  const int lane = tid & 63;
  const int wave = tid >> 6;
  const int wm = wave >> 1, wn = wave & 1;
  const int g = lane >> 4, r16 = lane & 15;
  const int m0 = blockIdx.y * 64, n0 = blockIdx.x * 64;
  __shared__ __align__(16) unsigned short Ah[2][64][40], Al[2][64][40];
  __shared__ __align__(16) unsigned short Bh[2][64][40], Bl[2][64][40];
  const int arow = tid >> 2;            // 0..63
  const int apart = (tid & 3) * 8;      // 8-elem (16 B) piece of a 32-elem row

  float4 a00, a01;
  u16x8 pb, plb;
#define LOADTILE(KT) do {                                                   \
    const size_t ko = (size_t)(KT) * 32 + apart;                            \
    const float* pa_ = A + (size_t)(m0 + arow) * 512 + ko;                  \
    a00 = *(const float4*)pa_;  a01 = *(const float4*)(pa_ + 4);            \
    pb  = *(const u16x8*)(BH + (size_t)(n0 + arow) * 512 + ko);             \
    plb = *(const u16x8*)(BL + (size_t)(n0 + arow) * 512 + ko);             \
  } while (0)
#define STORETILE(BUF) do {                                                 \
    u16x8 h0_, l0_;                                                         \
    split8(a00, a01, h0_, l0_);                                             \
    *(u16x8*)&Ah[BUF][arow][apart] = h0_;                                   \
    *(u16x8*)&Al[BUF][arow][apart] = l0_;                                   \
    *(u16x8*)&Bh[BUF][arow][apart] = pb;                                    \
    *(u16x8*)&Bl[BUF][arow][apart] = plb;                                   \
  } while (0)

  f32x4 accm[2][2], acce[2][2];
  #pragma unroll
  for (int mt = 0; mt < 2; ++mt)
    #pragma unroll
    for (int nt = 0; nt < 2; ++nt) {
      accm[mt][nt] = (f32x4){0.f, 0.f, 0.f, 0.f};
      acce[mt][nt] = (f32x4){0.f, 0.f, 0.f, 0.f};
    }

  LOADTILE(0);
  STORETILE(0);
  __syncthreads();

  for (int kt = 0; kt < 16; ++kt) {
    const int cur = kt & 1;
    if (kt + 1 < 16) LOADTILE(kt + 1);  // issue early; hides under compute
    bf16x8 ah[2], al[2], bh[2], bl[2];
    #pragma unroll
    for (int mt = 0; mt < 2; ++mt) {
      ah[mt] = *(const bf16x8*)&Ah[cur][wm * 32 + mt * 16 + r16][g * 8];
      al[mt] = *(const bf16x8*)&Al[cur][wm * 32 + mt * 16 + r16][g * 8];
    }
    #pragma unroll
    for (int nt = 0; nt < 2; ++nt) {
      bh[nt] = *(const bf16x8*)&Bh[cur][wn * 32 + nt * 16 + r16][g * 8];
      bl[nt] = *(const bf16x8*)&Bl[cur][wn * 32 + nt * 16 + r16][g * 8];
    }
    #pragma unroll
    for (int mt = 0; mt < 2; ++mt)
      #pragma unroll
      for (int nt = 0; nt < 2; ++nt) {
        accm[mt][nt] = __builtin_amdgcn_mfma_f32_16x16x32_bf16(ah[mt], bh[nt], accm[mt][nt], 0, 0, 0);
        acce[mt][nt] = __builtin_amdgcn_mfma_f32_16x16x32_bf16(al[mt], bh[nt], acce[mt][nt], 0, 0, 0);
        acce[mt][nt] = __builtin_amdgcn_mfma_f32_16x16x32_bf16(ah[mt], bl[nt], acce[mt][nt], 0, 0, 0);
      }
    if (kt + 1 < 16) STORETILE(cur ^ 1);  // other buffer: no hazard
    __syncthreads();                       // single barrier per k-tile
  }
#undef LOADTILE
#undef STORETILE

  #pragma unroll
  for (int mt = 0; mt < 2; ++mt)
    #pragma unroll
    for (int nt = 0; nt < 2; ++nt)
      #pragma unroll
      for (int jj = 0; jj < 4; ++jj) {
        float vsum = accm[mt][nt][jj] + acce[mt][nt][jj];
        int row = m0 + wm * 32 + mt * 16 + g * 4 + jj;
        int col = n0 + wn * 32 + nt * 16 + r16;
        C[(size_t)row * 512 + col] = __builtin_amdgcn_exp2f(vsum * K2SCALE);
      }
}

// ---------------- fused scores + softmax + context -----------------------------
// R7 structure; ONE change: the per-t reduction tree's levels 1,2,4,8 now use
// full-rate VALU DPP (quad_perm xor1/xor2 for the q-value-halving, row_ror:4/8
// for the quad sums) instead of ds_swizzle -- only xor16/xor32 remain DS ops.
// The old 7-deep ds+waitcnt chain (~280cy serial per t) was the prime suspect
// for the 27% VALU-idle. Final layout unchanged: lane<4 holds q=lane.
__global__ __launch_bounds__(512, 4) void attn(
    const float* __restrict__ ws, const float* __restrict__ uh,
    const float* __restrict__ enc, const float* __restrict__ va,
    float* __restrict__ out_c, float* __restrict__ out_e)
{
  const int tid  = threadIdx.x;
  const int wave = tid >> 6;
  const int lane = tid & 63;
  const int b  = blockIdx.x & 7;           // XCD-locality: batch <-> XCD
  const int q0 = (blockIdx.x >> 3) * QT;
  __shared__ float s_sc[QT][TE];           // 4 KB
  __shared__ float red[3][QT][DE];         // 24 KB, context partials
  const int fbase = lane * 8;              // lane owns 8 contiguous f

  float4 v0 = *(const float4*)(va + fbase);
  float4 v1 = *(const float4*)(va + fbase + 4);
  float v[8] = {v0.x, v0.y, v0.z, v0.w, v1.x, v1.y, v1.z, v1.w};

  float eu[QT][8];
  #pragma unroll
  for (int q = 0; q < QT; ++q) {
    const float* up = uh + (size_t)(b * TD + q0 + q) * DE + fbase;
    float4 u0 = *(const float4*)(up);
    float4 u1 = *(const float4*)(up + 4);
    eu[q][0] = u0.x; eu[q][1] = u0.y; eu[q][2] = u0.z; eu[q][3] = u0.w;
    eu[q][4] = u1.x; eu[q][5] = u1.y; eu[q][6] = u1.z; eu[q][7] = u1.w;
  }

  // ---- scores: wave owns t in [wave*32, wave*32+32), 1-deep prefetch on ws ----
  const int t0 = wave * 32;
  const float* wp = ws + (size_t)(b * TE + t0) * DE + fbase;
  float4 w0 = *(const float4*)(wp);
  float4 w1 = *(const float4*)(wp + 4);
  for (int t = t0; t < t0 + 32; ++t) {
    float cw[8] = {w0.x, w0.y, w0.z, w0.w, w1.x, w1.y, w1.z, w1.w};
    // prefetch next row; last iteration reads one row past (lands in uh[0],
    // still inside the same workspace allocation) and is unused.
    wp += DE;
    w0 = *(const float4*)(wp);
    w1 = *(const float4*)(wp + 4);
    float a[QT];
    #pragma unroll
    for (int q = 0; q < QT; ++q) {
      float A0 = fmaf(cw[0], eu[q][0], 1.f);
      float A1 = fmaf(cw[1], eu[q][1], 1.f);
      float A2 = fmaf(cw[2], eu[q][2], 1.f);
      float A3 = fmaf(cw[3], eu[q][3], 1.f);
      float B0 = fmaf(cw[4], eu[q][4], 1.f);
      float B1 = fmaf(cw[5], eu[q][5], 1.f);
      float B2 = fmaf(cw[6], eu[q][6], 1.f);
      float B3 = fmaf(cw[7], eu[q][7], 1.f);
      float n1 = fmaf(v[1], A0, v[0] * A1);
      float d1 = A0 * A1;
      float n2 = fmaf(v[3], A2, v[2] * A3);
      float d2 = A2 * A3;
      float N1 = fmaf(n2, d1, n1 * d2);
      float D1 = d1 * d2;
      float n3 = fmaf(v[5], B0, v[4] * B1);
      float d3 = B0 * B1;
      float n4 = fmaf(v[7], B2, v[6] * B3);
      float d4 = B2 * B3;
      float N2 = fmaf(n4, d3, n3 * d4);
      float D2 = d3 * d4;
      float s = N1 * __builtin_amdgcn_rcpf(D1);
      a[q] = fmaf(N2, __builtin_amdgcn_rcpf(D2), s);
    }
    // reduction tree: DPP for levels 1,2 (value-halving) + 4,8 (row sums);
    // DS only for xor16/xor32. Lane l<4 ends with q=l (same as before).
    {
      const bool h1 = lane & 1;
      float m0 = h1 ? a[1] : a[0], o0 = h1 ? a[0] : a[1];
      float m1 = h1 ? a[3] : a[2], o1 = h1 ? a[2] : a[3];
      float r0 = m0 + dpp_mov<0xB1>(o0);    // quad_perm [1,0,3,2] == xor1
      float r1 = m1 + dpp_mov<0xB1>(o1);
      const bool h2 = lane & 2;
      float mm = h2 ? r1 : r0, oo = h2 ? r0 : r1;
      float r = mm + dpp_mov<0x4E>(oo);     // quad_perm [2,3,0,1] == xor2
      r += dpp_mov<0x124>(r);               // row_ror:4  (sum quads)
      r += dpp_mov<0x128>(r);               // row_ror:8
      r += __shfl_xor(r, 16, 64);
      r += __shfl_xor(r, 32, 64);
      if (lane < QT) s_sc[lane][t] = -2.f * r;
    }
  }
  __syncthreads();

  // ---- softmax: waves 0..3 handle row = wave; waves 4..7 wait ----
  if (wave < QT) {
    const int r = wave;
    float x[4];
    #pragma unroll
    for (int i = 0; i < 4; ++i) x[i] = s_sc[r][lane + 64 * i];
    float m = fmaxf(fmaxf(x[0], x[1]), fmaxf(x[2], x[3]));
    #pragma unroll
    for (int off = 32; off >= 1; off >>= 1) m = fmaxf(m, __shfl_xor(m, off, 64));
    const float L2E = 1.4426950408889634f;
    float ssum = 0.f;
    #pragma unroll
    for (int i = 0; i < 4; ++i) { x[i] = __builtin_amdgcn_exp2f((x[i] - m) * L2E); ssum += x[i]; }
    #pragma unroll
    for (int off = 32; off >= 1; off >>= 1) ssum += __shfl_xor(ssum, off, 64);
    float inv = 1.f / ssum;
    float* oe = out_e + (size_t)(b * TD + q0 + r) * TE;
    #pragma unroll
    for (int i = 0; i < 4; ++i) {
      float e = x[i] * inv;
      s_sc[r][lane + 64 * i] = e;
      oe[lane + 64 * i] = e;
    }
  }
  __syncthreads();

  // ---- context: c[q][f4..f4+3] = sum_t e[q][t]*enc[b][t][f4..f4+3] ----
  {
    const int fgrp = tid >> 7;           // 0..3
    const int f4   = (tid & 127) * 4;
    float4 c[QT];
    #pragma unroll
    for (int q = 0; q < QT; ++q) c[q] = make_float4(0.f, 0.f, 0.f, 0.f);
    const float* eb = enc + (size_t)b * TE * DE + f4;
    const int tb = fgrp * 64;
    #pragma unroll 4
    for (int t = tb; t < tb + 64; ++t) {
      float4 ee = *(const float4*)(eb + (size_t)t * DE);
      #pragma unroll
      for (int q = 0; q < QT; ++q) {
        float w = s_sc[q][t];
        c[q].x = fmaf(w, ee.x, c[q].x);
        c[q].y = fmaf(w, ee.y, c[q].y);
        c[q].z = fmaf(w, ee.z, c[q].z);
        c[q].w = fmaf(w, ee.w, c[q].w);
      }
    }
    if (fgrp > 0) {
      #pragma unroll
      for (int q = 0; q < QT; ++q) *(float4*)&red[fgrp - 1][q][f4] = c[q];
    }
    __syncthreads();
    if (fgrp == 0) {
      #pragma unroll
      for (int q = 0; q < QT; ++q) {
        float4 r1 = *(const float4*)&red[0][q][f4];
        float4 r2 = *(const float4*)&red[1][q][f4];
        float4 r3 = *(const float4*)&red[2][q][f4];
        c[q].x += (r1.x + r2.x) + r3.x;
        c[q].y += (r1.y + r2.y) + r3.y;
        c[q].z += (r1.z + r2.z) + r3.z;
        c[q].w += (r1.w + r2.w) + r3.w;
        *(float4*)(out_c + (size_t)(b * TD + q0 + q) * DE + f4) = c[q];
      }
    }
  }
}

extern "C" void kernel_launch(void* const* d_in, const int* in_sizes, int n_in,
                              void* d_out, int out_size, void* d_ws, size_t ws_size,
                              hipStream_t stream) {
  const float* enc = (const float*)d_in[0];
  const float* dec = (const float*)d_in[1];
  const float* Wa  = (const float*)d_in[2];
  const float* Ua  = (const float*)d_in[3];
  const float* Va  = (const float*)d_in[4];
  float* out_c = (float*)d_out;
  float* out_e = out_c + (size_t)NB * TD * DE;          // c first, then e

  // workspace layout (10 MB):
  float* ws = (float*)d_ws;                             // ew = e^{2Ws}: 4 MB
  float* uh = ws + 1048576;                             // eu = e^{2Uh}: 4 MB
  unsigned short* BHw = (unsigned short*)(uh + 1048576);// 0.5 MB each
  unsigned short* BLw = BHw + 262144;
  unsigned short* BHu = BLw + 262144;
  unsigned short* BLu = BHu + 262144;

  convB<<<dim3(16, 16, 2), dim3(256), 0, stream>>>(Wa, BHw, BLw, Ua, BHu, BLu);
  gemm_mfma<<<dim3(8, 32, 2), dim3(256), 0, stream>>>(
      enc, BHw, BLw, ws, dec, BHu, BLu, uh);
  attn<<<dim3(NB * (TD / QT)), dim3(512), 0, stream>>>(
      ws, uh, enc, Va, out_c, out_e);
}

// Round 14
// 67.602 us; speedup vs baseline: 1.4870x; 1.0077x over previous
//
#include <hip/hip_runtime.h>

#define NB 8
#define TE 256
#define TD 256
#define DE 512
#define QT 4

// K2 = 2*log2(e): exp2(K2*x) = e^{2x}; tanh(x) = 1 - 2/(e^{2x}+1).
#define K2SCALE 2.8853900817779268f

typedef short bf16x8 __attribute__((ext_vector_type(8)));           // 8 bf16 (4 VGPR)
typedef float f32x4 __attribute__((ext_vector_type(4)));            // MFMA acc
typedef float f32x2 __attribute__((ext_vector_type(2)));            // v_pk_*_f32 pair
typedef unsigned short u16x8 __attribute__((ext_vector_type(8)));   // 16 B staging

// round-to-nearest-even f32 -> bf16
static __device__ __forceinline__ unsigned short f2bf(float x) {
  unsigned int u = __float_as_uint(x);
  u += 0x7fffu + ((u >> 16) & 1u);
  return (unsigned short)(u >> 16);
}

// split f32 -> hi (ROUNDED bf16) + lo (rounded residual).
static __device__ __forceinline__ void split8(
    const float4& x0, const float4& x1, u16x8& h, u16x8& l) {
  float xs[8] = {x0.x, x0.y, x0.z, x0.w, x1.x, x1.y, x1.z, x1.w};
  #pragma unroll
  for (int j = 0; j < 8; ++j) {
    unsigned short hh = f2bf(xs[j]);
    float hf = __uint_as_float((unsigned int)hh << 16);
    h[j] = hh;
    l[j] = f2bf(xs[j] - hf);
  }
}

// ---- convB: W [512x512] f32 -> TRANSPOSED hi/lo bf16 BT[n][k] (32x32 tiles) ----
// grid (16, 16, 2), 256 thr.  (R6-exact: chain minimum)
__global__ __launch_bounds__(256) void convB(
    const float* __restrict__ w0, unsigned short* __restrict__ h0, unsigned short* __restrict__ l0,
    const float* __restrict__ w1, unsigned short* __restrict__ h1, unsigned short* __restrict__ l1)
{
  const float* W = blockIdx.z ? w1 : w0;
  unsigned short* H = blockIdx.z ? h1 : h0;
  unsigned short* L = blockIdx.z ? l1 : l0;
  __shared__ unsigned short sh[32][33], sl[32][33];
  const int t = threadIdx.x;
  const int k0 = blockIdx.y * 32, n0 = blockIdx.x * 32;
  const int r = t >> 3, c = (t & 7) * 4;
  float4 x = *(const float4*)(W + (size_t)(k0 + r) * DE + n0 + c);
  float xs[4] = {x.x, x.y, x.z, x.w};
  #pragma unroll
  for (int j = 0; j < 4; ++j) {
    unsigned short hh = f2bf(xs[j]);
    float hf = __uint_as_float((unsigned int)hh << 16);
    sh[r][c + j] = hh;
    sl[r][c + j] = f2bf(xs[j] - hf);
  }
  __syncthreads();
  ushort4 oh, ol;
  oh.x = sh[c + 0][r]; oh.y = sh[c + 1][r]; oh.z = sh[c + 2][r]; oh.w = sh[c + 3][r];
  ol.x = sl[c + 0][r]; ol.y = sl[c + 1][r]; ol.z = sl[c + 2][r]; ol.w = sl[c + 3][r];
  *(ushort4*)(H + (size_t)(n0 + r) * DE + k0 + c) = oh;
  *(ushort4*)(L + (size_t)(n0 + r) * DE + k0 + c) = ol;
}

// ---- gemm_mfma: C = exp2(K2 * A@B), A f32 split in-register, dbuf LDS ---------
// R6-exact: BM=64 BN=64 KT=32, 256 thr (4 waves 2x2), wave-tile 32x32,
// grid (8, 32, 2) 2D decode.
__global__ __launch_bounds__(256) void gemm_mfma(
    const float* __restrict__ A0,
    const unsigned short* __restrict__ BH0, const unsigned short* __restrict__ BL0,
    float* __restrict__ C0,
    const float* __restrict__ A1,
    const unsigned short* __restrict__ BH1, const unsigned short* __restrict__ BL1,
    float* __restrict__ C1)
{
  const float*          A  = blockIdx.z ? A1  : A0;
  const unsigned short* BH = blockIdx.z ? BH1 : BH0;
  const unsigned short* BL = blockIdx.z ? BL1 : BL0;
  float*                C  = blockIdx.z ? C1  : C0;
  const int tid  = threadIdx.x;
  const int lane = tid & 63;
  const int wave = tid >> 6;
  const int wm = wave >> 1, wn = wave & 1;
  const int g = lane >> 4, r16 = lane & 15;
  const int m0 = blockIdx.y * 64, n0 = blockIdx.x * 64;
  __shared__ __align__(16) unsigned short Ah[2][64][40], Al[2][64][40];
  __shared__ __align__(16) unsigned short Bh[2][64][40], Bl[2][64][40];
  const int arow = tid >> 2;            // 0..63
  const int apart = (tid & 3) * 8;      // 8-elem (16 B) piece of a 32-elem row

  float4 a00, a01;
  u16x8 pb, plb;
#define LOADTILE(KT) do {                                                   \
    const size_t ko = (size_t)(KT) * 32 + apart;                            \
    const float* pa_ = A + (size_t)(m0 + arow) * 512 + ko;                  \
    a00 = *(const float4*)pa_;  a01 = *(const float4*)(pa_ + 4);            \
    pb  = *(const u16x8*)(BH + (size_t)(n0 + arow) * 512 + ko);             \
    plb = *(const u16x8*)(BL + (size_t)(n0 + arow) * 512 + ko);             \
  } while (0)
#define STORETILE(BUF) do {                                                 \
    u16x8 h0_, l0_;                                                         \
    split8(a00, a01, h0_, l0_);                                             \
    *(u16x8*)&Ah[BUF][arow][apart] = h0_;                                   \
    *(u16x8*)&Al[BUF][arow][apart] = l0_;                                   \
    *(u16x8*)&Bh[BUF][arow][apart] = pb;                                    \
    *(u16x8*)&Bl[BUF][arow][apart] = plb;                                   \
  } while (0)

  f32x4 accm[2][2], acce[2][2];
  #pragma unroll
  for (int mt = 0; mt < 2; ++mt)
    #pragma unroll
    for (int nt = 0; nt < 2; ++nt) {
      accm[mt][nt] = (f32x4){0.f, 0.f, 0.f, 0.f};
      acce[mt][nt] = (f32x4){0.f, 0.f, 0.f, 0.f};
    }

  LOADTILE(0);
  STORETILE(0);
  __syncthreads();

  for (int kt = 0; kt < 16; ++kt) {
    const int cur = kt & 1;
    if (kt + 1 < 16) LOADTILE(kt + 1);  // issue early; hides under compute
    bf16x8 ah[2], al[2], bh[2], bl[2];
    #pragma unroll
    for (int mt = 0; mt < 2; ++mt) {
      ah[mt] = *(const bf16x8*)&Ah[cur][wm * 32 + mt * 16 + r16][g * 8];
      al[mt] = *(const bf16x8*)&Al[cur][wm * 32 + mt * 16 + r16][g * 8];
    }
    #pragma unroll
    for (int nt = 0; nt < 2; ++nt) {
      bh[nt] = *(const bf16x8*)&Bh[cur][wn * 32 + nt * 16 + r16][g * 8];
      bl[nt] = *(const bf16x8*)&Bl[cur][wn * 32 + nt * 16 + r16][g * 8];
    }
    #pragma unroll
    for (int mt = 0; mt < 2; ++mt)
      #pragma unroll
      for (int nt = 0; nt < 2; ++nt) {
        accm[mt][nt] = __builtin_amdgcn_mfma_f32_16x16x32_bf16(ah[mt], bh[nt], accm[mt][nt], 0, 0, 0);
        acce[mt][nt] = __builtin_amdgcn_mfma_f32_16x16x32_bf16(al[mt], bh[nt], acce[mt][nt], 0, 0, 0);
        acce[mt][nt] = __builtin_amdgcn_mfma_f32_16x16x32_bf16(ah[mt], bl[nt], acce[mt][nt], 0, 0, 0);
      }
    if (kt + 1 < 16) STORETILE(cur ^ 1);  // other buffer: no hazard
    __syncthreads();                       // single barrier per k-tile
  }
#undef LOADTILE
#undef STORETILE

  #pragma unroll
  for (int mt = 0; mt < 2; ++mt)
    #pragma unroll
    for (int nt = 0; nt < 2; ++nt)
      #pragma unroll
      for (int jj = 0; jj < 4; ++jj) {
        float vsum = accm[mt][nt][jj] + acce[mt][nt][jj];
        int row = m0 + wm * 32 + mt * 16 + g * 4 + jj;
        int col = n0 + wn * 32 + nt * 16 + r16;
        C[(size_t)row * 512 + col] = __builtin_amdgcn_exp2f(vsum * K2SCALE);
      }
}

// ---------------- fused scores + softmax + context -----------------------------
// R7/R12 structure; ONE change: the score tree is packed across q-PAIRS as
// <2 x float> so LLVM emits v_pk_fma_f32 / v_pk_mul_f32 (2 f32 ops per issue
// slot, gfx90a+). euP/vP packing is register-neutral (same 32+16 VGPRs).
// rcp stays scalar (no packed rcp; count unchanged). Arithmetic per element is
// identical -> absmax bit-identical. Reduction butterfly: R12's proven DS form.
__global__ __launch_bounds__(512, 4) void attn(
    const float* __restrict__ ws, const float* __restrict__ uh,
    const float* __restrict__ enc, const float* __restrict__ va,
    float* __restrict__ out_c, float* __restrict__ out_e)
{
  const int tid  = threadIdx.x;
  const int wave = tid >> 6;
  const int lane = tid & 63;
  const int b  = blockIdx.x & 7;           // XCD-locality: batch <-> XCD
  const int q0 = (blockIdx.x >> 3) * QT;
  __shared__ float s_sc[QT][TE];           // 4 KB
  __shared__ float red[3][QT][DE];         // 24 KB, context partials
  const int fbase = lane * 8;              // lane owns 8 contiguous f

  float4 v0 = *(const float4*)(va + fbase);
  float4 v1 = *(const float4*)(va + fbase + 4);
  float v[8] = {v0.x, v0.y, v0.z, v0.w, v1.x, v1.y, v1.z, v1.w};
  f32x2 vP[8];
  #pragma unroll
  for (int j = 0; j < 8; ++j) vP[j] = (f32x2){v[j], v[j]};

  // euP[p][j] = (eu[2p][j], eu[2p+1][j])
  f32x2 euP[2][8];
  #pragma unroll
  for (int p = 0; p < 2; ++p) {
    const float* up0 = uh + (size_t)(b * TD + q0 + 2 * p) * DE + fbase;
    const float* up1 = up0 + DE;
    float4 a0 = *(const float4*)(up0);
    float4 a1 = *(const float4*)(up0 + 4);
    float4 b0 = *(const float4*)(up1);
    float4 b1 = *(const float4*)(up1 + 4);
    float ea[8] = {a0.x, a0.y, a0.z, a0.w, a1.x, a1.y, a1.z, a1.w};
    float eb[8] = {b0.x, b0.y, b0.z, b0.w, b1.x, b1.y, b1.z, b1.w};
    #pragma unroll
    for (int j = 0; j < 8; ++j) euP[p][j] = (f32x2){ea[j], eb[j]};
  }
  const f32x2 one2 = {1.f, 1.f};

  // ---- scores: wave owns t in [wave*32, wave*32+32), 1-deep prefetch on ws ----
  const int t0 = wave * 32;
  const float* wp = ws + (size_t)(b * TE + t0) * DE + fbase;
  float4 w0 = *(const float4*)(wp);
  float4 w1 = *(const float4*)(wp + 4);
  for (int t = t0; t < t0 + 32; ++t) {
    float cw[8] = {w0.x, w0.y, w0.z, w0.w, w1.x, w1.y, w1.z, w1.w};
    // prefetch next row; last iteration reads one row past (lands in uh[0],
    // still inside the same workspace allocation) and is unused.
    wp += DE;
    w0 = *(const float4*)(wp);
    w1 = *(const float4*)(wp + 4);
    f32x2 cw2[8];
    #pragma unroll
    for (int j = 0; j < 8; ++j) cw2[j] = (f32x2){cw[j], cw[j]};
    float a[QT];
    #pragma unroll
    for (int p = 0; p < 2; ++p) {
      f32x2 A0 = __builtin_elementwise_fma(cw2[0], euP[p][0], one2);
      f32x2 A1 = __builtin_elementwise_fma(cw2[1], euP[p][1], one2);
      f32x2 A2 = __builtin_elementwise_fma(cw2[2], euP[p][2], one2);
      f32x2 A3 = __builtin_elementwise_fma(cw2[3], euP[p][3], one2);
      f32x2 B0 = __builtin_elementwise_fma(cw2[4], euP[p][4], one2);
      f32x2 B1 = __builtin_elementwise_fma(cw2[5], euP[p][5], one2);
      f32x2 B2 = __builtin_elementwise_fma(cw2[6], euP[p][6], one2);
      f32x2 B3 = __builtin_elementwise_fma(cw2[7], euP[p][7], one2);
      f32x2 n1 = __builtin_elementwise_fma(vP[1], A0, vP[0] * A1);
      f32x2 d1 = A0 * A1;
      f32x2 n2 = __builtin_elementwise_fma(vP[3], A2, vP[2] * A3);
      f32x2 d2 = A2 * A3;
      f32x2 N1 = __builtin_elementwise_fma(n2, d1, n1 * d2);
      f32x2 D1 = d1 * d2;
      f32x2 n3 = __builtin_elementwise_fma(vP[5], B0, vP[4] * B1);
      f32x2 d3 = B0 * B1;
      f32x2 n4 = __builtin_elementwise_fma(vP[7], B2, vP[6] * B3);
      f32x2 d4 = B2 * B3;
      f32x2 N2 = __builtin_elementwise_fma(n4, d3, n3 * d4);
      f32x2 D2 = d3 * d4;
      float s0 = N1.x * __builtin_amdgcn_rcpf(D1.x);
      a[2 * p + 0] = fmaf(N2.x, __builtin_amdgcn_rcpf(D2.x), s0);
      float s1 = N1.y * __builtin_amdgcn_rcpf(D1.y);
      a[2 * p + 1] = fmaf(N2.y, __builtin_amdgcn_rcpf(D2.y), s1);
    }
    // value-halving butterfly: 4 partials over 64 lanes -> lane l<4 holds q=l
    {
      const bool h1 = lane & 1;
      float m0 = h1 ? a[1] : a[0], o0 = h1 ? a[0] : a[1];
      float m1 = h1 ? a[3] : a[2], o1 = h1 ? a[2] : a[3];
      float r0 = m0 + __shfl_xor(o0, 1, 64);
      float r1 = m1 + __shfl_xor(o1, 1, 64);
      const bool h2 = lane & 2;
      float mm = h2 ? r1 : r0, oo = h2 ? r0 : r1;
      float r = mm + __shfl_xor(oo, 2, 64);
      r += __shfl_xor(r, 4, 64);
      r += __shfl_xor(r, 8, 64);
      r += __shfl_xor(r, 16, 64);
      r += __shfl_xor(r, 32, 64);
      if (lane < QT) s_sc[lane][t] = -2.f * r;
    }
  }
  __syncthreads();

  // ---- softmax: waves 0..3 handle row = wave; waves 4..7 wait ----
  if (wave < QT) {
    const int r = wave;
    float x[4];
    #pragma unroll
    for (int i = 0; i < 4; ++i) x[i] = s_sc[r][lane + 64 * i];
    float m = fmaxf(fmaxf(x[0], x[1]), fmaxf(x[2], x[3]));
    #pragma unroll
    for (int off = 32; off >= 1; off >>= 1) m = fmaxf(m, __shfl_xor(m, off, 64));
    const float L2E = 1.4426950408889634f;
    float ssum = 0.f;
    #pragma unroll
    for (int i = 0; i < 4; ++i) { x[i] = __builtin_amdgcn_exp2f((x[i] - m) * L2E); ssum += x[i]; }
    #pragma unroll
    for (int off = 32; off >= 1; off >>= 1) ssum += __shfl_xor(ssum, off, 64);
    float inv = 1.f / ssum;
    float* oe = out_e + (size_t)(b * TD + q0 + r) * TE;
    #pragma unroll
    for (int i = 0; i < 4; ++i) {
      float e = x[i] * inv;
      s_sc[r][lane + 64 * i] = e;
      oe[lane + 64 * i] = e;
    }
  }
  __syncthreads();

  // ---- context: c[q][f4..f4+3] = sum_t e[q][t]*enc[b][t][f4..f4+3] ----
  {
    const int fgrp = tid >> 7;           // 0..3
    const int f4   = (tid & 127) * 4;
    float4 c[QT];
    #pragma unroll
    for (int q = 0; q < QT; ++q) c[q] = make_float4(0.f, 0.f, 0.f, 0.f);
    const float* eb = enc + (size_t)b * TE * DE + f4;
    const int tb = fgrp * 64;
    #pragma unroll 4
    for (int t = tb; t < tb + 64; ++t) {
      float4 ee = *(const float4*)(eb + (size_t)t * DE);
      #pragma unroll
      for (int q = 0; q < QT; ++q) {
        float w = s_sc[q][t];
        c[q].x = fmaf(w, ee.x, c[q].x);
        c[q].y = fmaf(w, ee.y, c[q].y);
        c[q].z = fmaf(w, ee.z, c[q].z);
        c[q].w = fmaf(w, ee.w, c[q].w);
      }
    }
    if (fgrp > 0) {
      #pragma unroll
      for (int q = 0; q < QT; ++q) *(float4*)&red[fgrp - 1][q][f4] = c[q];
    }
    __syncthreads();
    if (fgrp == 0) {
      #pragma unroll
      for (int q = 0; q < QT; ++q) {
        float4 r1 = *(const float4*)&red[0][q][f4];
        float4 r2 = *(const float4*)&red[1][q][f4];
        float4 r3 = *(const float4*)&red[2][q][f4];
        c[q].x += (r1.x + r2.x) + r3.x;
        c[q].y += (r1.y + r2.y) + r3.y;
        c[q].z += (r1.z + r2.z) + r3.z;
        c[q].w += (r1.w + r2.w) + r3.w;
        *(float4*)(out_c + (size_t)(b * TD + q0 + q) * DE + f4) = c[q];
      }
    }
  }
}

extern "C" void kernel_launch(void* const* d_in, const int* in_sizes, int n_in,
                              void* d_out, int out_size, void* d_ws, size_t ws_size,
                              hipStream_t stream) {
  const float* enc = (const float*)d_in[0];
  const float* dec = (const float*)d_in[1];
  const float* Wa  = (const float*)d_in[2];
  const float* Ua  = (const float*)d_in[3];
  const float* Va  = (const float*)d_in[4];
  float* out_c = (float*)d_out;
  float* out_e = out_c + (size_t)NB * TD * DE;          // c first, then e

  // workspace layout (10 MB):
  float* ws = (float*)d_ws;                             // ew = e^{2Ws}: 4 MB
  float* uh = ws + 1048576;                             // eu = e^{2Uh}: 4 MB
  unsigned short* BHw = (unsigned short*)(uh + 1048576);// 0.5 MB each
  unsigned short* BLw = BHw + 262144;
  unsigned short* BHu = BLw + 262144;
  unsigned short* BLu = BHu + 262144;

  convB<<<dim3(16, 16, 2), dim3(256), 0, stream>>>(Wa, BHw, BLw, Ua, BHu, BLu);
  gemm_mfma<<<dim3(8, 32, 2), dim3(256), 0, stream>>>(
      enc, BHw, BLw, ws, dec, BHu, BLu, uh);
  attn<<<dim3(NB * (TD / QT)), dim3(512), 0, stream>>>(
      ws, uh, enc, Va, out_c, out_e);
}